// Round 1
// baseline (437.619 us; speedup 1.0000x reference)
//
#include <hip/hip_runtime.h>
#include <cmath>

#define GHEADS 8
#define GHID 64
#define NEG 0.2f

// ---------------- CSR build ----------------
__global__ void zero_int_kernel(int* p, int n) {
  int i = blockIdx.x * blockDim.x + threadIdx.x;
  if (i < n) p[i] = 0;
}

__global__ void count_kernel(const int* __restrict__ ei, int* __restrict__ counts, int E, int Nn) {
  int e = blockIdx.x * blockDim.x + threadIdx.x;
  if (e >= E + Nn) return;
  int d = (e < E) ? ei[E + e] : (e - E);
  atomicAdd(&counts[d], 1);
}

__global__ __launch_bounds__(1024) void scan_kernel(const int* __restrict__ counts,
                                                    int* __restrict__ row_ptr,
                                                    int* __restrict__ cursor,
                                                    int n, int total) {
  __shared__ int sums[1024];
  int t = threadIdx.x;
  int per = (n + 1023) >> 10;
  int base = t * per;
  int s = 0;
  for (int i = 0; i < per; ++i) { int idx = base + i; if (idx < n) s += counts[idx]; }
  sums[t] = s;
  __syncthreads();
  for (int st = 1; st < 1024; st <<= 1) {
    int v = (t >= st) ? sums[t - st] : 0;
    __syncthreads();
    sums[t] += v;
    __syncthreads();
  }
  int off = (t == 0) ? 0 : sums[t - 1];
  for (int i = 0; i < per; ++i) {
    int idx = base + i;
    if (idx < n) { row_ptr[idx] = off; cursor[idx] = off; off += counts[idx]; }
  }
  if (t == 0) row_ptr[n] = total;
}

__global__ void scatter_kernel(const int* __restrict__ ei, int* __restrict__ cursor,
                               int* __restrict__ src_sorted, int E, int Nn) {
  int e = blockIdx.x * blockDim.x + threadIdx.x;
  if (e >= E + Nn) return;
  int s, d;
  if (e < E) { s = ei[e]; d = ei[E + e]; } else { s = e - E; d = e - E; }
  int pos = atomicAdd(&cursor[d], 1);
  src_sorted[pos] = s;
}

// ---------------- fp32 tiled GEMM: C[M,Nc] = A[M,K] @ B[K,Nc] ----------------
#define BM 64
#define BN 64
#define BKK 16
__global__ __launch_bounds__(256) void gemm_kernel(const float* __restrict__ A,
                                                   const float* __restrict__ B,
                                                   float* __restrict__ C,
                                                   int M, int K, int Nc) {
  __shared__ float As[BKK][BM + 4];  // row stride 68 floats = 272B (16B multiple)
  __shared__ float Bs[BKK][BN + 4];
  int tid = threadIdx.x;
  int tx = tid & 15, ty = tid >> 4;
  int rowBase = blockIdx.x * BM;
  int colBase = blockIdx.y * BN;

  int la_m = tid >> 2;        // 0..63
  int la_k = (tid & 3) * 4;   // 0,4,8,12
  int lb_k = tid >> 4;        // 0..15
  int lb_n = (tid & 15) * 4;  // 0..60

  float acc[4][4] = {};

  for (int k0 = 0; k0 < K; k0 += BKK) {
    int ar = rowBase + la_m;
    float4 av = make_float4(0.f, 0.f, 0.f, 0.f);
    if (ar < M) av = *reinterpret_cast<const float4*>(&A[(size_t)ar * K + k0 + la_k]);
    As[la_k + 0][la_m] = av.x;
    As[la_k + 1][la_m] = av.y;
    As[la_k + 2][la_m] = av.z;
    As[la_k + 3][la_m] = av.w;
    float4 bv = *reinterpret_cast<const float4*>(&B[(size_t)(k0 + lb_k) * Nc + colBase + lb_n]);
    *reinterpret_cast<float4*>(&Bs[lb_k][lb_n]) = bv;
    __syncthreads();
#pragma unroll
    for (int k = 0; k < BKK; ++k) {
      const float4 a = *reinterpret_cast<const float4*>(&As[k][ty * 4]);
      const float4 b = *reinterpret_cast<const float4*>(&Bs[k][tx * 4]);
      float avv[4] = {a.x, a.y, a.z, a.w};
      float bvv[4] = {b.x, b.y, b.z, b.w};
#pragma unroll
      for (int i = 0; i < 4; ++i)
#pragma unroll
        for (int j = 0; j < 4; ++j) acc[i][j] = fmaf(avv[i], bvv[j], acc[i][j]);
    }
    __syncthreads();
  }
#pragma unroll
  for (int i = 0; i < 4; ++i) {
    int r = rowBase + ty * 4 + i;
    if (r < M) {
      float4 v = make_float4(acc[i][0], acc[i][1], acc[i][2], acc[i][3]);
      *reinterpret_cast<float4*>(&C[(size_t)r * Nc + colBase + tx * 4]) = v;
    }
  }
}

// ---------------- alpha dot products ----------------
__global__ __launch_bounds__(512) void alpha8_kernel(const float* __restrict__ Hf,
                                                     const float* __restrict__ asrc,
                                                     const float* __restrict__ adst,
                                                     float* __restrict__ als,
                                                     float* __restrict__ ald, int Nn) {
  int n = blockIdx.x;
  int t = threadIdx.x;
  int w = t >> 6, c = t & 63;
  float hv = Hf[(size_t)n * 512 + t];
  float ps = hv * asrc[t];
  float pd = hv * adst[t];
  for (int s = 32; s; s >>= 1) {
    ps += __shfl_down(ps, s);
    pd += __shfl_down(pd, s);
  }
  if (c == 0) {
    als[n * GHEADS + w] = ps;
    ald[n * GHEADS + w] = pd;
  }
}

__global__ __launch_bounds__(64) void alpha1_kernel(const float* __restrict__ Hf,
                                                    const float* __restrict__ asrc,
                                                    const float* __restrict__ adst,
                                                    float* __restrict__ als,
                                                    float* __restrict__ ald, int Nn) {
  int n = blockIdx.x;
  int c = threadIdx.x;
  float hv = Hf[(size_t)n * GHID + c];
  float ps = hv * asrc[c];
  float pd = hv * adst[c];
  for (int s = 32; s; s >>= 1) {
    ps += __shfl_down(ps, s);
    pd += __shfl_down(pd, s);
  }
  if (c == 0) {
    als[n] = ps;
    ald[n] = pd;
  }
}

// ---------------- fused segment softmax + aggregate, 8 heads ----------------
#define CHUNK 64
__global__ __launch_bounds__(512) void agg8_kernel(const float* __restrict__ Hf,   // [N,512]
                                                   const float* __restrict__ als,  // [N,8]
                                                   const float* __restrict__ ald,  // [N,8]
                                                   const float* __restrict__ bias, // [512]
                                                   const int* __restrict__ row_ptr,
                                                   const int* __restrict__ src_sorted,
                                                   float* __restrict__ out,        // [N,512]
                                                   int Nn, int do_elu) {
  int n = blockIdx.x;
  int t = threadIdx.x;
  int start = row_ptr[n];
  int deg = row_ptr[n + 1] - start;

  __shared__ float red[512];
  __shared__ float wbuf[CHUNK][GHEADS];
  __shared__ int srcbuf[CHUNK];
  __shared__ float mh[GHEADS], sh[GHEADS], aldn[GHEADS];

  if (t < GHEADS) {
    aldn[t] = ald[n * GHEADS + t];
    sh[t] = 0.f;
  }
  __syncthreads();

  // phase 1: per-head max of als over incoming neighbors (leaky_relu monotone)
  int es = t >> 3, h = t & 7;
  float pm = -INFINITY;
  for (int e = es; e < deg; e += 64) {
    int s = src_sorted[start + e];
    pm = fmaxf(pm, als[s * GHEADS + h]);
  }
  red[t] = pm;
  __syncthreads();
  for (int st = 256; st >= 8; st >>= 1) {
    if (t < st) red[t] = fmaxf(red[t], red[t + st]);
    __syncthreads();
  }
  if (t < GHEADS) {
    float v = red[t] + aldn[t];
    mh[t] = v > 0.f ? v : NEG * v;
  }
  __syncthreads();

  // phase 2: weights + weighted aggregation
  int hc = t >> 6;  // head for accumulation; output column == t
  float acc = 0.f;
  for (int base = 0; base < deg; base += CHUNK) {
    int m = min(CHUNK, deg - base);
    if (t < m) srcbuf[t] = src_sorted[start + base + t];
    __syncthreads();
    if (es < m) {
      float l = als[srcbuf[es] * GHEADS + h] + aldn[h];
      l = l > 0.f ? l : NEG * l;
      wbuf[es][h] = expf(l - mh[h]);
    }
    __syncthreads();
    if (t < GHEADS) {
      float ssum = 0.f;
      for (int e = 0; e < m; ++e) ssum += wbuf[e][t];
      sh[t] += ssum;
    }
    for (int e = 0; e < m; ++e) {
      acc = fmaf(wbuf[e][hc], Hf[(size_t)srcbuf[e] * 512 + t], acc);
    }
    __syncthreads();
  }

  float v = acc / (sh[hc] + 1e-16f) + bias[t];
  if (do_elu) v = v > 0.f ? v : expm1f(v);
  out[(size_t)n * 512 + t] = v;
}

// ---------------- fused aggregate, 1 head (layer 3) ----------------
__global__ __launch_bounds__(64) void agg1_kernel(const float* __restrict__ Hf,   // [N,64]
                                                  const float* __restrict__ als,  // [N]
                                                  const float* __restrict__ ald,  // [N]
                                                  const float* __restrict__ bias, // [64]
                                                  const int* __restrict__ row_ptr,
                                                  const int* __restrict__ src_sorted,
                                                  float* __restrict__ out,        // [N,64]
                                                  int Nn) {
  int n = blockIdx.x;
  int t = threadIdx.x;
  int start = row_ptr[n];
  int deg = row_ptr[n + 1] - start;
  float aldn = ald[n];

  float pm = -INFINITY;
  for (int e = t; e < deg; e += 64) pm = fmaxf(pm, als[src_sorted[start + e]]);
  for (int s = 32; s; s >>= 1) pm = fmaxf(pm, __shfl_down(pm, s));
  pm = __shfl(pm, 0);
  float mv = pm + aldn;
  mv = mv > 0.f ? mv : NEG * mv;

  __shared__ float wbuf[64];
  __shared__ int srcbuf[64];
  float acc = 0.f, ssum = 0.f;
  for (int base = 0; base < deg; base += 64) {
    int m = min(64, deg - base);
    float w = 0.f;
    if (t < m) {
      int s = src_sorted[start + base + t];
      srcbuf[t] = s;
      float l = als[s] + aldn;
      l = l > 0.f ? l : NEG * l;
      w = expf(l - mv);
    }
    float cs = w;
    for (int s = 32; s; s >>= 1) cs += __shfl_down(cs, s);
    ssum += __shfl(cs, 0);
    wbuf[t] = w;
    __syncthreads();
    for (int e = 0; e < m; ++e) acc = fmaf(wbuf[e], Hf[(size_t)srcbuf[e] * GHID + t], acc);
    __syncthreads();
  }
  out[(size_t)n * GHID + t] = acc / (ssum + 1e-16f) + bias[t];
}

// ---------------- classifier + log_softmax ----------------
__global__ __launch_bounds__(64) void cls_kernel(const float* __restrict__ X,   // [N,64]
                                                 const float* __restrict__ lw,  // [64,2]
                                                 const float* __restrict__ lb,  // [2]
                                                 float* __restrict__ out, int Nn) {
  int n = blockIdx.x;
  int c = threadIdx.x;
  float v = X[(size_t)n * GHID + c];
  float p0 = v * lw[c * 2 + 0];
  float p1 = v * lw[c * 2 + 1];
  for (int s = 32; s; s >>= 1) {
    p0 += __shfl_down(p0, s);
    p1 += __shfl_down(p1, s);
  }
  if (c == 0) {
    p0 += lb[0];
    p1 += lb[1];
    float mx = fmaxf(p0, p1);
    float lse = mx + logf(expf(p0 - mx) + expf(p1 - mx));
    out[n * 2 + 0] = p0 - lse;
    out[n * 2 + 1] = p1 - lse;
  }
}

extern "C" void kernel_launch(void* const* d_in, const int* in_sizes, int n_in,
                              void* d_out, int out_size, void* d_ws, size_t ws_size,
                              hipStream_t stream) {
  (void)n_in; (void)out_size; (void)ws_size;
  const float* x     = (const float*)d_in[0];
  const int*   ei    = (const int*)d_in[1];
  const float* W1    = (const float*)d_in[2];
  const float* asrc1 = (const float*)d_in[3];
  const float* adst1 = (const float*)d_in[4];
  const float* b1    = (const float*)d_in[5];
  const float* W2    = (const float*)d_in[6];
  const float* asrc2 = (const float*)d_in[7];
  const float* adst2 = (const float*)d_in[8];
  const float* b2    = (const float*)d_in[9];
  const float* W3    = (const float*)d_in[10];
  const float* asrc3 = (const float*)d_in[11];
  const float* adst3 = (const float*)d_in[12];
  const float* b3    = (const float*)d_in[13];
  const float* linW  = (const float*)d_in[14];
  const float* linb  = (const float*)d_in[15];
  float* out = (float*)d_out;

  int Nn = in_sizes[0] / 256;
  int E  = in_sizes[1] / 2;
  int E2 = E + Nn;

  float* Xb  = (float*)d_ws;                      // [N,512]
  float* Hb  = Xb + (size_t)Nn * 512;             // [N,512]
  float* als = Hb + (size_t)Nn * 512;             // [N,8]
  float* ald = als + (size_t)Nn * GHEADS;         // [N,8]
  int* counts = (int*)(ald + (size_t)Nn * GHEADS);
  int* cursor = counts + Nn;
  int* row_ptr = cursor + Nn;
  int* src_sorted = row_ptr + (Nn + 1);

  // CSR build (edges identical for all layers)
  zero_int_kernel<<<(Nn + 255) / 256, 256, 0, stream>>>(counts, Nn);
  count_kernel<<<(E2 + 255) / 256, 256, 0, stream>>>(ei, counts, E, Nn);
  scan_kernel<<<1, 1024, 0, stream>>>(counts, row_ptr, cursor, Nn, E2);
  scatter_kernel<<<(E2 + 255) / 256, 256, 0, stream>>>(ei, cursor, src_sorted, E, Nn);

  int gm = (Nn + 63) / 64;
  // layer 1: 256 -> 8x64 concat
  gemm_kernel<<<dim3(gm, 8), 256, 0, stream>>>(x, W1, Hb, Nn, 256, 512);
  alpha8_kernel<<<Nn, 512, 0, stream>>>(Hb, asrc1, adst1, als, ald, Nn);
  agg8_kernel<<<Nn, 512, 0, stream>>>(Hb, als, ald, b1, row_ptr, src_sorted, Xb, Nn, 1);
  // layer 2: 512 -> 8x64 concat
  gemm_kernel<<<dim3(gm, 8), 256, 0, stream>>>(Xb, W2, Hb, Nn, 512, 512);
  alpha8_kernel<<<Nn, 512, 0, stream>>>(Hb, asrc2, adst2, als, ald, Nn);
  agg8_kernel<<<Nn, 512, 0, stream>>>(Hb, als, ald, b2, row_ptr, src_sorted, Xb, Nn, 1);
  // layer 3: 512 -> 64, 1 head, mean(=identity)
  gemm_kernel<<<dim3(gm, 1), 256, 0, stream>>>(Xb, W3, Hb, Nn, 512, 64);
  alpha1_kernel<<<Nn, 64, 0, stream>>>(Hb, asrc3, adst3, als, ald, Nn);
  agg1_kernel<<<Nn, 64, 0, stream>>>(Hb, als, ald, b3, row_ptr, src_sorted, Xb, Nn);
  // classifier
  cls_kernel<<<Nn, 64, 0, stream>>>(Xb, linW, linb, out, Nn);
}

// Round 2
// 383.949 us; speedup vs baseline: 1.1398x; 1.1398x over previous
//
#include <hip/hip_runtime.h>
#include <cmath>

#define NEG 0.2f

typedef __bf16 bf16x8 __attribute__((ext_vector_type(8)));
typedef __bf16 bf16x4 __attribute__((ext_vector_type(4)));
typedef float  f32x4  __attribute__((ext_vector_type(4)));

__device__ __forceinline__ void async16(const __bf16* g, __bf16* l) {
  __builtin_amdgcn_global_load_lds(
      (const __attribute__((address_space(1))) void*)g,
      (__attribute__((address_space(3))) void*)l, 16, 0, 0);
}
__device__ __forceinline__ f32x4 mfma16(bf16x8 a, bf16x8 b, f32x4 c) {
  return __builtin_amdgcn_mfma_f32_16x16x32_bf16(a, b, c, 0, 0, 0);
}

// ---------------- CSR build ----------------
__global__ void zero_int_kernel(int* p, int n) {
  int i = blockIdx.x * blockDim.x + threadIdx.x;
  if (i < n) p[i] = 0;
}

__global__ void count_kernel(const int* __restrict__ ei, int* __restrict__ counts, int E, int Nn) {
  int e = blockIdx.x * blockDim.x + threadIdx.x;
  if (e >= E + Nn) return;
  int d = (e < E) ? ei[E + e] : (e - E);
  atomicAdd(&counts[d], 1);
}

__global__ __launch_bounds__(1024) void scan_kernel(const int* __restrict__ counts,
                                                    int* __restrict__ row_ptr,
                                                    int* __restrict__ cursor,
                                                    int n, int total) {
  __shared__ int sums[1024];
  int t = threadIdx.x;
  int per = (n + 1023) >> 10;
  int base = t * per;
  int s = 0;
  for (int i = 0; i < per; ++i) { int idx = base + i; if (idx < n) s += counts[idx]; }
  sums[t] = s;
  __syncthreads();
  for (int st = 1; st < 1024; st <<= 1) {
    int v = (t >= st) ? sums[t - st] : 0;
    __syncthreads();
    sums[t] += v;
    __syncthreads();
  }
  int off = (t == 0) ? 0 : sums[t - 1];
  for (int i = 0; i < per; ++i) {
    int idx = base + i;
    if (idx < n) { row_ptr[idx] = off; cursor[idx] = off; off += counts[idx]; }
  }
  if (t == 0) row_ptr[n] = total;
}

__global__ void scatter_kernel(const int* __restrict__ ei, int* __restrict__ cursor,
                               int* __restrict__ src_sorted, int E, int Nn) {
  int e = blockIdx.x * blockDim.x + threadIdx.x;
  if (e >= E + Nn) return;
  int s, d;
  if (e < E) { s = ei[e]; d = ei[E + e]; } else { s = e - E; d = e - E; }
  int pos = atomicAdd(&cursor[d], 1);
  src_sorted[pos] = s;
}

// ---------------- prep: fp32 -> split bf16 ----------------
__global__ void split_kernel(const float* __restrict__ in, __bf16* __restrict__ oh,
                             __bf16* __restrict__ ol, int n) {
  int i = blockIdx.x * blockDim.x + threadIdx.x;
  if (i < n) {
    float v = in[i];
    __bf16 h = (__bf16)v;
    oh[i] = h;
    ol[i] = (__bf16)(v - (float)h);
  }
}

// W [K][Nc] row-major -> Wt split [Nc][K]
__global__ void tsplit_kernel(const float* __restrict__ W, __bf16* __restrict__ oth,
                              __bf16* __restrict__ otl, int K, int Nc) {
  int i = blockIdx.x * blockDim.x + threadIdx.x;
  if (i < K * Nc) {
    int k = i / Nc, c = i % Nc;
    float v = W[i];
    __bf16 h = (__bf16)v;
    oth[(size_t)c * K + k] = h;
    otl[(size_t)c * K + k] = (__bf16)(v - (float)h);
  }
}

// ---------------- split-bf16 MFMA GEMM ----------------
// C[M,Nc] = (Ah+Al)[M,K] @ (Bh+Bl) where Bt is [Nc][K] (pre-transposed)
// tile: BM=128, BN=64, BK=32; 256 threads (4 waves), each wave owns 32 rows.
template <bool BF16OUT>
__global__ __launch_bounds__(256) void gemm_split(
    const __bf16* __restrict__ Ah, const __bf16* __restrict__ Al,
    const __bf16* __restrict__ Bth, const __bf16* __restrict__ Btl,
    __bf16* __restrict__ Cb, float* __restrict__ Cf,
    int M, int K, int Nc) {
  // LDS layouts: A: [k8(4)][row(128)][8], B: [k8(4)][col(64)][8]
  __shared__ __bf16 sAh[4096], sAl[4096], sBh[2048], sBl[2048];

  int tid = threadIdx.x;
  int lane = tid & 63, wave = tid >> 6;
  int rowBase = blockIdx.x * 128, colBase = blockIdx.y * 64;

  // A staging: chunk c in {0,1}: flat = c*256+tid -> k8 = c*2+(tid>>7), row = tid&127
  int arow = tid & 127;
  int grow = rowBase + arow; if (grow >= M) grow = M - 1;
  int ak8 = tid >> 7;  // 0..1
  const __bf16* gah0 = Ah + (size_t)grow * K + ak8 * 8;
  const __bf16* gah1 = gah0 + 16;
  const __bf16* gal0 = Al + (size_t)grow * K + ak8 * 8;
  const __bf16* gal1 = gal0 + 16;
  // B staging: flat = tid -> k8 = tid>>6, col = tid&63
  int bcol = tid & 63, bk8 = tid >> 6;
  const __bf16* gbh = Bth + (size_t)(colBase + bcol) * K + bk8 * 8;
  const __bf16* gbl = Btl + (size_t)(colBase + bcol) * K + bk8 * 8;

  // wave-uniform LDS bases (lane writes base + lane*16B)
  int wl = tid & ~63;
  __bf16* dAh0 = sAh + wl * 8;
  __bf16* dAh1 = sAh + (256 + wl) * 8;
  __bf16* dAl0 = sAl + wl * 8;
  __bf16* dAl1 = sAl + (256 + wl) * 8;
  __bf16* dBh  = sBh + wl * 8;
  __bf16* dBl  = sBl + wl * 8;

  int r16 = lane & 15, koct = lane >> 4;
  int aoff = (koct * 128 + wave * 32 + r16) * 8;  // +128 elems for fm=1
  int boff = (koct * 64 + r16) * 8;               // +128 elems per fn

  f32x4 acc[2][4] = {};

  for (int k0 = 0; k0 < K; k0 += 32) {
    __syncthreads();  // previous tile fully consumed
    async16(gah0, dAh0); async16(gah1, dAh1);
    async16(gal0, dAl0); async16(gal1, dAl1);
    async16(gbh, dBh);   async16(gbl, dBl);
    gah0 += 32; gah1 += 32; gal0 += 32; gal1 += 32; gbh += 32; gbl += 32;
    __syncthreads();  // vmcnt drained by compiler before barrier -> data visible

    bf16x8 a_h[2], a_l[2], b_h[4], b_l[4];
    a_h[0] = *reinterpret_cast<const bf16x8*>(sAh + aoff);
    a_h[1] = *reinterpret_cast<const bf16x8*>(sAh + aoff + 128);
    a_l[0] = *reinterpret_cast<const bf16x8*>(sAl + aoff);
    a_l[1] = *reinterpret_cast<const bf16x8*>(sAl + aoff + 128);
#pragma unroll
    for (int fn = 0; fn < 4; ++fn) {
      b_h[fn] = *reinterpret_cast<const bf16x8*>(sBh + boff + fn * 128);
      b_l[fn] = *reinterpret_cast<const bf16x8*>(sBl + boff + fn * 128);
    }
#pragma unroll
    for (int fm = 0; fm < 2; ++fm)
#pragma unroll
      for (int fn = 0; fn < 4; ++fn) {
        acc[fm][fn] = mfma16(a_h[fm], b_h[fn], acc[fm][fn]);
        acc[fm][fn] = mfma16(a_l[fm], b_h[fn], acc[fm][fn]);
        acc[fm][fn] = mfma16(a_h[fm], b_l[fn], acc[fm][fn]);
      }
  }

  // C/D layout: col = lane&15, row = (lane>>4)*4 + r
#pragma unroll
  for (int fm = 0; fm < 2; ++fm)
#pragma unroll
    for (int fn = 0; fn < 4; ++fn) {
      int col = colBase + fn * 16 + r16;
#pragma unroll
      for (int r = 0; r < 4; ++r) {
        int row = rowBase + wave * 32 + fm * 16 + koct * 4 + r;
        if (row < M) {
          float v = acc[fm][fn][r];
          if (BF16OUT) Cb[(size_t)row * Nc + col] = (__bf16)v;
          else         Cf[(size_t)row * Nc + col] = v;
        }
      }
    }
}

// ---------------- alpha dot products (bf16 h) ----------------
__global__ __launch_bounds__(512) void alpha8b_kernel(const __bf16* __restrict__ Hb,
                                                      const float* __restrict__ asrc,
                                                      const float* __restrict__ adst,
                                                      float* __restrict__ als,
                                                      float* __restrict__ ald, int Nn) {
  int n = blockIdx.x, t = threadIdx.x;
  int w = t >> 6, c = t & 63;
  float hv = (float)Hb[(size_t)n * 512 + t];
  float ps = hv * asrc[t];
  float pd = hv * adst[t];
  for (int s = 32; s; s >>= 1) {
    ps += __shfl_down(ps, s);
    pd += __shfl_down(pd, s);
  }
  if (c == 0) { als[n * 8 + w] = ps; ald[n * 8 + w] = pd; }
}

__global__ __launch_bounds__(64) void alpha1_kernel(const float* __restrict__ Hf,
                                                    const float* __restrict__ asrc,
                                                    const float* __restrict__ adst,
                                                    float* __restrict__ als,
                                                    float* __restrict__ ald, int Nn) {
  int n = blockIdx.x, c = threadIdx.x;
  float hv = Hf[(size_t)n * 64 + c];
  float ps = hv * asrc[c];
  float pd = hv * adst[c];
  for (int s = 32; s; s >>= 1) {
    ps += __shfl_down(ps, s);
    pd += __shfl_down(pd, s);
  }
  if (c == 0) { als[n] = ps; ald[n] = pd; }
}

// ---------------- fused segment softmax + aggregate, 8 heads, bf16 gather ----
// 512 threads: e4 = t>>7 (4 parallel edges), cg = t&127 (4 bf16 cols each).
__global__ __launch_bounds__(512) void agg8_kernel(const __bf16* __restrict__ Hb,  // [N,512] bf16
                                                   const float* __restrict__ als,  // [N,8]
                                                   const float* __restrict__ ald,  // [N,8]
                                                   const float* __restrict__ bias, // [512]
                                                   const int* __restrict__ row_ptr,
                                                   const int* __restrict__ src_sorted,
                                                   __bf16* __restrict__ Oh,        // [N,512]
                                                   __bf16* __restrict__ Ol,        // [N,512]
                                                   int Nn) {
  int n = blockIdx.x, t = threadIdx.x;
  int start = row_ptr[n], deg = row_ptr[n + 1] - start;

  __shared__ float smem[2048];  // phase1: red[512]; end: cross-e4 reduce [4][128][4]
  __shared__ float wbuf[64][8];
  __shared__ int srcbuf[64];
  __shared__ float mh[8], sh[8], aldn[8];

  if (t < 8) { aldn[t] = ald[n * 8 + t]; sh[t] = 0.f; }
  __syncthreads();

  // phase 1: per-head max of als over neighbors (leaky_relu monotone)
  int es = t >> 3, h8 = t & 7;
  float pm = -INFINITY;
  for (int e = es; e < deg; e += 64)
    pm = fmaxf(pm, als[src_sorted[start + e] * 8 + h8]);
  smem[t] = pm;
  __syncthreads();
  for (int st = 256; st >= 8; st >>= 1) {
    if (t < st) smem[t] = fmaxf(smem[t], smem[t + st]);
    __syncthreads();
  }
  if (t < 8) {
    float v = smem[t] + aldn[t];
    mh[t] = v > 0.f ? v : NEG * v;
  }
  __syncthreads();

  // phase 2: weights + 4-edge-parallel weighted aggregation
  int e4 = t >> 7, cg = t & 127, hh = cg >> 4;
  float a0 = 0.f, a1 = 0.f, a2 = 0.f, a3 = 0.f;
  for (int base = 0; base < deg; base += 64) {
    int m = min(64, deg - base);
    if (t < m) srcbuf[t] = src_sorted[start + base + t];
    __syncthreads();
    if (es < m) {
      float l = als[srcbuf[es] * 8 + h8] + aldn[h8];
      l = l > 0.f ? l : NEG * l;
      wbuf[es][h8] = expf(l - mh[h8]);
    }
    __syncthreads();
    if (t < 8) {
      float ssum = 0.f;
      for (int e = 0; e < m; ++e) ssum += wbuf[e][t];
      sh[t] += ssum;
    }
    for (int eb = 0; eb < m; eb += 4) {
      int e = eb + e4;
      if (e < m) {  // wave-uniform (e4 constant per wave)
        float w = wbuf[e][hh];
        bf16x4 v = *reinterpret_cast<const bf16x4*>(Hb + (size_t)srcbuf[e] * 512 + cg * 4);
        a0 = fmaf(w, (float)v.x, a0);
        a1 = fmaf(w, (float)v.y, a1);
        a2 = fmaf(w, (float)v.z, a2);
        a3 = fmaf(w, (float)v.w, a3);
      }
    }
    __syncthreads();
  }

  // cross-e4 reduce + epilogue (bias, elu, split-bf16 write)
  smem[t * 4 + 0] = a0;
  smem[t * 4 + 1] = a1;
  smem[t * 4 + 2] = a2;
  smem[t * 4 + 3] = a3;
  __syncthreads();
  if (t < 128) {
    int cg0 = t;
    float inv = 1.f / (sh[cg0 >> 4] + 1e-16f);
    bf16x4 vh, vl;
#pragma unroll
    for (int j = 0; j < 4; ++j) {
      float v = smem[cg0 * 4 + j] + smem[512 + cg0 * 4 + j] +
                smem[1024 + cg0 * 4 + j] + smem[1536 + cg0 * 4 + j];
      v = v * inv + bias[cg0 * 4 + j];
      v = v > 0.f ? v : expm1f(v);
      __bf16 h = (__bf16)v;
      vh[j] = h;
      vl[j] = (__bf16)(v - (float)h);
    }
    *reinterpret_cast<bf16x4*>(Oh + (size_t)n * 512 + cg0 * 4) = vh;
    *reinterpret_cast<bf16x4*>(Ol + (size_t)n * 512 + cg0 * 4) = vl;
  }
}

// ---------------- fused aggregate, 1 head (layer 3, fp32) ----------------
__global__ __launch_bounds__(64) void agg1_kernel(const float* __restrict__ Hf,   // [N,64]
                                                  const float* __restrict__ als,  // [N]
                                                  const float* __restrict__ ald,  // [N]
                                                  const float* __restrict__ bias, // [64]
                                                  const int* __restrict__ row_ptr,
                                                  const int* __restrict__ src_sorted,
                                                  float* __restrict__ out,        // [N,64]
                                                  int Nn) {
  int n = blockIdx.x, t = threadIdx.x;
  int start = row_ptr[n], deg = row_ptr[n + 1] - start;
  float aldn = ald[n];

  float pm = -INFINITY;
  for (int e = t; e < deg; e += 64) pm = fmaxf(pm, als[src_sorted[start + e]]);
  for (int s = 32; s; s >>= 1) pm = fmaxf(pm, __shfl_down(pm, s));
  pm = __shfl(pm, 0);
  float mv = pm + aldn;
  mv = mv > 0.f ? mv : NEG * mv;

  __shared__ float wbuf[64];
  __shared__ int srcbuf[64];
  float acc = 0.f, ssum = 0.f;
  for (int base = 0; base < deg; base += 64) {
    int m = min(64, deg - base);
    float w = 0.f;
    if (t < m) {
      int s = src_sorted[start + base + t];
      srcbuf[t] = s;
      float l = als[s] + aldn;
      l = l > 0.f ? l : NEG * l;
      w = expf(l - mv);
    }
    float cs = w;
    for (int s = 32; s; s >>= 1) cs += __shfl_down(cs, s);
    ssum += __shfl(cs, 0);
    wbuf[t] = w;
    __syncthreads();
    for (int e = 0; e < m; ++e) acc = fmaf(wbuf[e], Hf[(size_t)srcbuf[e] * 64 + t], acc);
    __syncthreads();
  }
  out[(size_t)n * 64 + t] = acc / (ssum + 1e-16f) + bias[t];
}

// ---------------- classifier + log_softmax ----------------
__global__ __launch_bounds__(64) void cls_kernel(const float* __restrict__ X,   // [N,64]
                                                 const float* __restrict__ lw,  // [64,2]
                                                 const float* __restrict__ lb,  // [2]
                                                 float* __restrict__ out, int Nn) {
  int n = blockIdx.x, c = threadIdx.x;
  float v = X[(size_t)n * 64 + c];
  float p0 = v * lw[c * 2 + 0];
  float p1 = v * lw[c * 2 + 1];
  for (int s = 32; s; s >>= 1) {
    p0 += __shfl_down(p0, s);
    p1 += __shfl_down(p1, s);
  }
  if (c == 0) {
    p0 += lb[0];
    p1 += lb[1];
    float mx = fmaxf(p0, p1);
    float lse = mx + logf(expf(p0 - mx) + expf(p1 - mx));
    out[n * 2 + 0] = p0 - lse;
    out[n * 2 + 1] = p1 - lse;
  }
}

extern "C" void kernel_launch(void* const* d_in, const int* in_sizes, int n_in,
                              void* d_out, int out_size, void* d_ws, size_t ws_size,
                              hipStream_t stream) {
  (void)n_in; (void)out_size; (void)ws_size;
  const float* x     = (const float*)d_in[0];
  const int*   ei    = (const int*)d_in[1];
  const float* W1    = (const float*)d_in[2];
  const float* asrc1 = (const float*)d_in[3];
  const float* adst1 = (const float*)d_in[4];
  const float* b1    = (const float*)d_in[5];
  const float* W2    = (const float*)d_in[6];
  const float* asrc2 = (const float*)d_in[7];
  const float* adst2 = (const float*)d_in[8];
  const float* b2    = (const float*)d_in[9];
  const float* W3    = (const float*)d_in[10];
  const float* asrc3 = (const float*)d_in[11];
  const float* adst3 = (const float*)d_in[12];
  const float* b3    = (const float*)d_in[13];
  const float* linW  = (const float*)d_in[14];
  const float* linb  = (const float*)d_in[15];
  float* out = (float*)d_out;

  int Nn = in_sizes[0] / 256;
  int E  = in_sizes[1] / 2;
  int E2 = E + Nn;

  char* w = (char*)d_ws;
  auto carve = [&](size_t bytes) {
    char* p = w;
    w += (bytes + 63) & ~(size_t)63;
    return p;
  };
  __bf16* xsh  = (__bf16*)carve((size_t)Nn * 256 * 2);
  __bf16* xsl  = (__bf16*)carve((size_t)Nn * 256 * 2);
  __bf16* Ahb  = (__bf16*)carve((size_t)Nn * 512 * 2);
  __bf16* Alb  = (__bf16*)carve((size_t)Nn * 512 * 2);
  __bf16* Hb16 = (__bf16*)carve((size_t)Nn * 512 * 2);
  float*  Hb3  = (float*)carve((size_t)Nn * 64 * 4);
  float*  X3   = (float*)carve((size_t)Nn * 64 * 4);
  float*  als  = (float*)carve((size_t)Nn * 8 * 4);
  float*  ald  = (float*)carve((size_t)Nn * 8 * 4);
  __bf16* W1th = (__bf16*)carve(256 * 512 * 2);
  __bf16* W1tl = (__bf16*)carve(256 * 512 * 2);
  __bf16* W2th = (__bf16*)carve(512 * 512 * 2);
  __bf16* W2tl = (__bf16*)carve(512 * 512 * 2);
  __bf16* W3th = (__bf16*)carve(512 * 64 * 2);
  __bf16* W3tl = (__bf16*)carve(512 * 64 * 2);
  int* counts     = (int*)carve((size_t)Nn * 4);
  int* cursor     = (int*)carve((size_t)Nn * 4);
  int* row_ptr    = (int*)carve(((size_t)Nn + 1) * 4);
  int* src_sorted = (int*)carve((size_t)E2 * 4);

  // CSR build (same edge set for all layers)
  zero_int_kernel<<<(Nn + 255) / 256, 256, 0, stream>>>(counts, Nn);
  count_kernel<<<(E2 + 255) / 256, 256, 0, stream>>>(ei, counts, E, Nn);
  scan_kernel<<<1, 1024, 0, stream>>>(counts, row_ptr, cursor, Nn, E2);
  scatter_kernel<<<(E2 + 255) / 256, 256, 0, stream>>>(ei, cursor, src_sorted, E, Nn);

  // input / weight prep
  split_kernel<<<((Nn * 256) + 255) / 256, 256, 0, stream>>>(x, xsh, xsl, Nn * 256);
  tsplit_kernel<<<(256 * 512 + 255) / 256, 256, 0, stream>>>(W1, W1th, W1tl, 256, 512);
  tsplit_kernel<<<(512 * 512 + 255) / 256, 256, 0, stream>>>(W2, W2th, W2tl, 512, 512);
  tsplit_kernel<<<(512 * 64 + 255) / 256, 256, 0, stream>>>(W3, W3th, W3tl, 512, 64);

  int gm = (Nn + 127) / 128;
  // layer 1: 256 -> 8x64 concat
  gemm_split<true><<<dim3(gm, 8), 256, 0, stream>>>(xsh, xsl, W1th, W1tl, Hb16, nullptr, Nn, 256, 512);
  alpha8b_kernel<<<Nn, 512, 0, stream>>>(Hb16, asrc1, adst1, als, ald, Nn);
  agg8_kernel<<<Nn, 512, 0, stream>>>(Hb16, als, ald, b1, row_ptr, src_sorted, Ahb, Alb, Nn);
  // layer 2: 512 -> 8x64 concat
  gemm_split<true><<<dim3(gm, 8), 256, 0, stream>>>(Ahb, Alb, W2th, W2tl, Hb16, nullptr, Nn, 512, 512);
  alpha8b_kernel<<<Nn, 512, 0, stream>>>(Hb16, asrc2, adst2, als, ald, Nn);
  agg8_kernel<<<Nn, 512, 0, stream>>>(Hb16, als, ald, b2, row_ptr, src_sorted, Ahb, Alb, Nn);
  // layer 3: 512 -> 64, 1 head
  gemm_split<false><<<dim3(gm, 1), 256, 0, stream>>>(Ahb, Alb, W3th, W3tl, nullptr, Hb3, Nn, 512, 64);
  alpha1_kernel<<<Nn, 64, 0, stream>>>(Hb3, asrc3, adst3, als, ald, Nn);
  agg1_kernel<<<Nn, 64, 0, stream>>>(Hb3, als, ald, b3, row_ptr, src_sorted, X3, Nn);
  // classifier
  cls_kernel<<<Nn, 64, 0, stream>>>(X3, linW, linb, out, Nn);
}

// Round 3
// 328.180 us; speedup vs baseline: 1.3335x; 1.1699x over previous
//
#include <hip/hip_runtime.h>
#include <cmath>

#define NEG 0.2f

typedef __bf16 bf16x8 __attribute__((ext_vector_type(8)));
typedef __bf16 bf16x4 __attribute__((ext_vector_type(4)));
typedef float  f32x4  __attribute__((ext_vector_type(4)));

__device__ __forceinline__ void async16(const __bf16* g, __bf16* l) {
  __builtin_amdgcn_global_load_lds(
      (const __attribute__((address_space(1))) void*)g,
      (__attribute__((address_space(3))) void*)l, 16, 0, 0);
}
__device__ __forceinline__ f32x4 mfma16(bf16x8 a, bf16x8 b, f32x4 c) {
  return __builtin_amdgcn_mfma_f32_16x16x32_bf16(a, b, c, 0, 0, 0);
}

// ---------------- CSR build ----------------
__global__ void zero_int_kernel(int* p, int n) {
  int i = blockIdx.x * blockDim.x + threadIdx.x;
  if (i < n) p[i] = 0;
}

__global__ void count_kernel(const int* __restrict__ ei, int* __restrict__ counts, int E, int Nn) {
  int e = blockIdx.x * blockDim.x + threadIdx.x;
  if (e >= E + Nn) return;
  int d = (e < E) ? ei[E + e] : (e - E);
  atomicAdd(&counts[d], 1);
}

__global__ __launch_bounds__(1024) void scan_kernel(const int* __restrict__ counts,
                                                    int* __restrict__ row_ptr,
                                                    int* __restrict__ cursor,
                                                    int n, int total) {
  __shared__ int sums[1024];
  int t = threadIdx.x;
  int per = (n + 1023) >> 10;
  int base = t * per;
  int s = 0;
  for (int i = 0; i < per; ++i) { int idx = base + i; if (idx < n) s += counts[idx]; }
  sums[t] = s;
  __syncthreads();
  for (int st = 1; st < 1024; st <<= 1) {
    int v = (t >= st) ? sums[t - st] : 0;
    __syncthreads();
    sums[t] += v;
    __syncthreads();
  }
  int off = (t == 0) ? 0 : sums[t - 1];
  for (int i = 0; i < per; ++i) {
    int idx = base + i;
    if (idx < n) { row_ptr[idx] = off; cursor[idx] = off; off += counts[idx]; }
  }
  if (t == 0) row_ptr[n] = total;
}

__global__ void scatter_kernel(const int* __restrict__ ei, int* __restrict__ cursor,
                               int* __restrict__ src_sorted, int E, int Nn) {
  int e = blockIdx.x * blockDim.x + threadIdx.x;
  if (e >= E + Nn) return;
  int s, d;
  if (e < E) { s = ei[e]; d = ei[E + e]; } else { s = e - E; d = e - E; }
  int pos = atomicAdd(&cursor[d], 1);
  src_sorted[pos] = s;
}

// ---------------- prep: fp32 -> split bf16 ----------------
__global__ void split_kernel(const float* __restrict__ in, __bf16* __restrict__ oh,
                             __bf16* __restrict__ ol, int n) {
  int i = blockIdx.x * blockDim.x + threadIdx.x;
  if (i < n) {
    float v = in[i];
    __bf16 h = (__bf16)v;
    oh[i] = h;
    ol[i] = (__bf16)(v - (float)h);
  }
}

// W [K][Nc] row-major -> Wt split [Nc][K]
__global__ void tsplit_kernel(const float* __restrict__ W, __bf16* __restrict__ oth,
                              __bf16* __restrict__ otl, int K, int Nc) {
  int i = blockIdx.x * blockDim.x + threadIdx.x;
  if (i < K * Nc) {
    int k = i / Nc, c = i % Nc;
    float v = W[i];
    __bf16 h = (__bf16)v;
    oth[(size_t)c * K + k] = h;
    otl[(size_t)c * K + k] = (__bf16)(v - (float)h);
  }
}

// ---------------- split-bf16 MFMA GEMM, 2-phase double-buffered ----------------
// C[M,Nc] = (Ah+Al)[M,K] @ (Bh+Bl), Bt pre-transposed [Nc][K].
// tile BM=128, BN=64, BK=32; 256 threads (4 waves), wave owns 32 rows.
template <bool BF16OUT>
__global__ __launch_bounds__(256) void gemm_split(
    const __bf16* __restrict__ Ah, const __bf16* __restrict__ Al,
    const __bf16* __restrict__ Bth, const __bf16* __restrict__ Btl,
    __bf16* __restrict__ Cb, float* __restrict__ Cf,
    int M, int K, int Nc) {
  // layouts per buffer: A [k8(4)][row(128)][8], B [k8(4)][col(64)][8]
  __shared__ __bf16 sAh[2][4096], sAl[2][4096], sBh[2][2048], sBl[2][2048];

  int tid = threadIdx.x;
  int lane = tid & 63, wave = tid >> 6;
  int rowBase = blockIdx.x * 128, colBase = blockIdx.y * 64;

  int arow = tid & 127;
  int grow = rowBase + arow; if (grow >= M) grow = M - 1;
  int ak8 = tid >> 7;  // 0..1
  const __bf16* gA_h = Ah + (size_t)grow * K + ak8 * 8;
  const __bf16* gA_l = Al + (size_t)grow * K + ak8 * 8;
  int bcol = tid & 63, bk8 = tid >> 6;
  const __bf16* gB_h = Bth + (size_t)(colBase + bcol) * K + bk8 * 8;
  const __bf16* gB_l = Btl + (size_t)(colBase + bcol) * K + bk8 * 8;

  int wl = tid & ~63;  // wave-uniform LDS slot base (HW adds lane*16B)
  int r16 = lane & 15, koct = lane >> 4;
  int aoff = (koct * 128 + wave * 32 + r16) * 8;
  int boff = (koct * 64 + r16) * 8;

  f32x4 acc[2][4] = {};
  int nt = K >> 5;

#define STAGE(buf, k0)                                         \
  do {                                                         \
    async16(gA_h + (k0),      sAh[buf] + wl * 8);              \
    async16(gA_h + (k0) + 16, sAh[buf] + (256 + wl) * 8);      \
    async16(gA_l + (k0),      sAl[buf] + wl * 8);              \
    async16(gA_l + (k0) + 16, sAl[buf] + (256 + wl) * 8);      \
    async16(gB_h + (k0),      sBh[buf] + wl * 8);               \
    async16(gB_l + (k0),      sBl[buf] + wl * 8);               \
  } while (0)

  STAGE(0, 0);
  for (int kt = 0; kt < nt; ++kt) {
    __syncthreads();  // drains this wave's vmcnt -> buf kt&1 fully staged
    if (kt + 1 < nt) STAGE((kt + 1) & 1, (kt + 1) * 32);  // fly under compute
    int b = kt & 1;

    bf16x8 a_h[2], a_l[2], b_h[4], b_l[4];
    a_h[0] = *reinterpret_cast<const bf16x8*>(sAh[b] + aoff);
    a_h[1] = *reinterpret_cast<const bf16x8*>(sAh[b] + aoff + 128);
    a_l[0] = *reinterpret_cast<const bf16x8*>(sAl[b] + aoff);
    a_l[1] = *reinterpret_cast<const bf16x8*>(sAl[b] + aoff + 128);
#pragma unroll
    for (int fn = 0; fn < 4; ++fn) {
      b_h[fn] = *reinterpret_cast<const bf16x8*>(sBh[b] + boff + fn * 128);
      b_l[fn] = *reinterpret_cast<const bf16x8*>(sBl[b] + boff + fn * 128);
    }
#pragma unroll
    for (int fm = 0; fm < 2; ++fm)
#pragma unroll
      for (int fn = 0; fn < 4; ++fn) {
        acc[fm][fn] = mfma16(a_h[fm], b_h[fn], acc[fm][fn]);
        acc[fm][fn] = mfma16(a_l[fm], b_h[fn], acc[fm][fn]);
        acc[fm][fn] = mfma16(a_h[fm], b_l[fn], acc[fm][fn]);
      }
  }
#undef STAGE

  // C/D layout: col = lane&15, row = (lane>>4)*4 + r
#pragma unroll
  for (int fm = 0; fm < 2; ++fm)
#pragma unroll
    for (int fn = 0; fn < 4; ++fn) {
      int col = colBase + fn * 16 + r16;
#pragma unroll
      for (int r = 0; r < 4; ++r) {
        int row = rowBase + wave * 32 + fm * 16 + koct * 4 + r;
        if (row < M) {
          float v = acc[fm][fn][r];
          if (BF16OUT) Cb[(size_t)row * Nc + col] = (__bf16)v;
          else         Cf[(size_t)row * Nc + col] = v;
        }
      }
    }
}

// ---------------- alpha dot products ----------------
__global__ __launch_bounds__(512) void alpha8b_kernel(const __bf16* __restrict__ Hb,
                                                      const float* __restrict__ asrc,
                                                      const float* __restrict__ adst,
                                                      float* __restrict__ als,
                                                      float* __restrict__ ald, int Nn) {
  int n = blockIdx.x, t = threadIdx.x;
  int w = t >> 6, c = t & 63;
  float hv = (float)Hb[(size_t)n * 512 + t];
  float ps = hv * asrc[t];
  float pd = hv * adst[t];
  for (int s = 32; s; s >>= 1) {
    ps += __shfl_down(ps, s);
    pd += __shfl_down(pd, s);
  }
  if (c == 0) { als[n * 8 + w] = ps; ald[n * 8 + w] = pd; }
}

__global__ __launch_bounds__(64) void alpha1_kernel(const float* __restrict__ Hf,
                                                    const float* __restrict__ asrc,
                                                    const float* __restrict__ adst,
                                                    float* __restrict__ als,
                                                    float* __restrict__ ald, int Nn) {
  int n = blockIdx.x, c = threadIdx.x;
  float hv = Hf[(size_t)n * 64 + c];
  float ps = hv * asrc[c];
  float pd = hv * adst[c];
  for (int s = 32; s; s >>= 1) {
    ps += __shfl_down(ps, s);
    pd += __shfl_down(pd, s);
  }
  if (c == 0) { als[n] = ps; ald[n] = pd; }
}

// ---------------- fused softmax+aggregate, 8 heads: one WAVE per node --------
// lane owns 8 bf16 cols (head hh = lane>>3); barrier-free, LDS-free.
__global__ __launch_bounds__(256) void agg8_kernel(const __bf16* __restrict__ Hb,  // [N,512]
                                                   const float* __restrict__ als,  // [N,8]
                                                   const float* __restrict__ ald,  // [N,8]
                                                   const float* __restrict__ bias, // [512]
                                                   const int* __restrict__ row_ptr,
                                                   const int* __restrict__ src_sorted,
                                                   __bf16* __restrict__ Oh,        // [N,512]
                                                   __bf16* __restrict__ Ol,        // [N,512]
                                                   int Nn) {
  int n = (blockIdx.x * 256 + threadIdx.x) >> 6;
  if (n >= Nn) return;
  int lane = threadIdx.x & 63;
  int hh = lane >> 3;
  int start = row_ptr[n], deg = row_ptr[n + 1] - start;
  float aldn = ald[n * 8 + hh];

  // phase 1: per-head neighbor max of als (leaky_relu monotone).
  // lane scans head (lane&7) over edges e ≡ lane>>3 (mod 8); xor-reduce 8/16/32.
  float pm = -INFINITY;
  for (int e = (lane >> 3); e < deg; e += 8)
    pm = fmaxf(pm, als[src_sorted[start + e] * 8 + (lane & 7)]);
  pm = fmaxf(pm, __shfl_xor(pm, 8));
  pm = fmaxf(pm, __shfl_xor(pm, 16));
  pm = fmaxf(pm, __shfl_xor(pm, 32));
  float m = __shfl(pm, hh) + aldn;  // lane hh holds head hh's max
  m = m > 0.f ? m : NEG * m;

  // phase 2: 4-deep unrolled gather; every lane computes its head's weight
  // redundantly -> denominator needs no reduction at all.
  float acc[8] = {};
  float ssum = 0.f;
  const __bf16* hcol = Hb + lane * 8;
  for (int e0 = 0; e0 < deg; e0 += 4) {
    int idx[4];
    float av[4];
    bf16x8 v[4];
#pragma unroll
    for (int i = 0; i < 4; ++i) {
      int e = e0 + i;
      if (e > deg - 1) e = deg - 1;
      idx[i] = src_sorted[start + e];
    }
#pragma unroll
    for (int i = 0; i < 4; ++i) av[i] = als[idx[i] * 8 + hh];
#pragma unroll
    for (int i = 0; i < 4; ++i)
      v[i] = *reinterpret_cast<const bf16x8*>(hcol + (size_t)idx[i] * 512);
#pragma unroll
    for (int i = 0; i < 4; ++i) {
      float l = av[i] + aldn;
      l = l > 0.f ? l : NEG * l;
      float w = (e0 + i < deg) ? expf(l - m) : 0.f;
      ssum += w;
#pragma unroll
      for (int j = 0; j < 8; ++j) acc[j] = fmaf(w, (float)v[i][j], acc[j]);
    }
  }

  float inv = 1.f / (ssum + 1e-16f);
  bf16x8 vh, vl;
#pragma unroll
  for (int j = 0; j < 8; ++j) {
    float v = acc[j] * inv + bias[lane * 8 + j];
    v = v > 0.f ? v : expm1f(v);
    __bf16 h = (__bf16)v;
    vh[j] = h;
    vl[j] = (__bf16)(v - (float)h);
  }
  *reinterpret_cast<bf16x8*>(Oh + (size_t)n * 512 + lane * 8) = vh;
  *reinterpret_cast<bf16x8*>(Ol + (size_t)n * 512 + lane * 8) = vl;
}

// ---------------- fused aggregate, 1 head: one wave per node ----------------
__global__ __launch_bounds__(256) void agg1_kernel(const float* __restrict__ Hf,   // [N,64]
                                                   const float* __restrict__ als,  // [N]
                                                   const float* __restrict__ ald,  // [N]
                                                   const float* __restrict__ bias, // [64]
                                                   const int* __restrict__ row_ptr,
                                                   const int* __restrict__ src_sorted,
                                                   float* __restrict__ out,        // [N,64]
                                                   int Nn) {
  int n = (blockIdx.x * 256 + threadIdx.x) >> 6;
  if (n >= Nn) return;
  int lane = threadIdx.x & 63;
  int start = row_ptr[n], deg = row_ptr[n + 1] - start;
  float aldn = ald[n];

  float pm = -INFINITY;
  for (int e = lane; e < deg; e += 64) pm = fmaxf(pm, als[src_sorted[start + e]]);
  for (int s = 32; s; s >>= 1) pm = fmaxf(pm, __shfl_xor(pm, s));
  float m = pm + aldn;
  m = m > 0.f ? m : NEG * m;

  float acc = 0.f, ssum = 0.f;
  for (int e0 = 0; e0 < deg; e0 += 4) {
    int idx[4];
    float av[4], hv[4];
#pragma unroll
    for (int i = 0; i < 4; ++i) {
      int e = e0 + i;
      if (e > deg - 1) e = deg - 1;
      idx[i] = src_sorted[start + e];
    }
#pragma unroll
    for (int i = 0; i < 4; ++i) av[i] = als[idx[i]];
#pragma unroll
    for (int i = 0; i < 4; ++i) hv[i] = Hf[(size_t)idx[i] * 64 + lane];
#pragma unroll
    for (int i = 0; i < 4; ++i) {
      float l = av[i] + aldn;
      l = l > 0.f ? l : NEG * l;
      float w = (e0 + i < deg) ? expf(l - m) : 0.f;
      ssum += w;
      acc = fmaf(w, hv[i], acc);
    }
  }
  out[(size_t)n * 64 + lane] = acc / (ssum + 1e-16f) + bias[lane];
}

// ---------------- classifier + log_softmax ----------------
__global__ __launch_bounds__(64) void cls_kernel(const float* __restrict__ X,   // [N,64]
                                                 const float* __restrict__ lw,  // [64,2]
                                                 const float* __restrict__ lb,  // [2]
                                                 float* __restrict__ out, int Nn) {
  int n = blockIdx.x, c = threadIdx.x;
  float v = X[(size_t)n * 64 + c];
  float p0 = v * lw[c * 2 + 0];
  float p1 = v * lw[c * 2 + 1];
  for (int s = 32; s; s >>= 1) {
    p0 += __shfl_down(p0, s);
    p1 += __shfl_down(p1, s);
  }
  if (c == 0) {
    p0 += lb[0];
    p1 += lb[1];
    float mx = fmaxf(p0, p1);
    float lse = mx + logf(expf(p0 - mx) + expf(p1 - mx));
    out[n * 2 + 0] = p0 - lse;
    out[n * 2 + 1] = p1 - lse;
  }
}

extern "C" void kernel_launch(void* const* d_in, const int* in_sizes, int n_in,
                              void* d_out, int out_size, void* d_ws, size_t ws_size,
                              hipStream_t stream) {
  (void)n_in; (void)out_size; (void)ws_size;
  const float* x     = (const float*)d_in[0];
  const int*   ei    = (const int*)d_in[1];
  const float* W1    = (const float*)d_in[2];
  const float* asrc1 = (const float*)d_in[3];
  const float* adst1 = (const float*)d_in[4];
  const float* b1    = (const float*)d_in[5];
  const float* W2    = (const float*)d_in[6];
  const float* asrc2 = (const float*)d_in[7];
  const float* adst2 = (const float*)d_in[8];
  const float* b2    = (const float*)d_in[9];
  const float* W3    = (const float*)d_in[10];
  const float* asrc3 = (const float*)d_in[11];
  const float* adst3 = (const float*)d_in[12];
  const float* b3    = (const float*)d_in[13];
  const float* linW  = (const float*)d_in[14];
  const float* linb  = (const float*)d_in[15];
  float* out = (float*)d_out;

  int Nn = in_sizes[0] / 256;
  int E  = in_sizes[1] / 2;
  int E2 = E + Nn;

  char* w = (char*)d_ws;
  auto carve = [&](size_t bytes) {
    char* p = w;
    w += (bytes + 63) & ~(size_t)63;
    return p;
  };
  __bf16* xsh  = (__bf16*)carve((size_t)Nn * 256 * 2);
  __bf16* xsl  = (__bf16*)carve((size_t)Nn * 256 * 2);
  __bf16* Ahb  = (__bf16*)carve((size_t)Nn * 512 * 2);
  __bf16* Alb  = (__bf16*)carve((size_t)Nn * 512 * 2);
  __bf16* Hb16 = (__bf16*)carve((size_t)Nn * 512 * 2);
  float*  Hb3  = (float*)carve((size_t)Nn * 64 * 4);
  float*  X3   = (float*)carve((size_t)Nn * 64 * 4);
  float*  als  = (float*)carve((size_t)Nn * 8 * 4);
  float*  ald  = (float*)carve((size_t)Nn * 8 * 4);
  __bf16* W1th = (__bf16*)carve(256 * 512 * 2);
  __bf16* W1tl = (__bf16*)carve(256 * 512 * 2);
  __bf16* W2th = (__bf16*)carve(512 * 512 * 2);
  __bf16* W2tl = (__bf16*)carve(512 * 512 * 2);
  __bf16* W3th = (__bf16*)carve(512 * 64 * 2);
  __bf16* W3tl = (__bf16*)carve(512 * 64 * 2);
  int* counts     = (int*)carve((size_t)Nn * 4);
  int* cursor     = (int*)carve((size_t)Nn * 4);
  int* row_ptr    = (int*)carve(((size_t)Nn + 1) * 4);
  int* src_sorted = (int*)carve((size_t)E2 * 4);

  // CSR build (same edge set for all layers)
  zero_int_kernel<<<(Nn + 255) / 256, 256, 0, stream>>>(counts, Nn);
  count_kernel<<<(E2 + 255) / 256, 256, 0, stream>>>(ei, counts, E, Nn);
  scan_kernel<<<1, 1024, 0, stream>>>(counts, row_ptr, cursor, Nn, E2);
  scatter_kernel<<<(E2 + 255) / 256, 256, 0, stream>>>(ei, cursor, src_sorted, E, Nn);

  // input / weight prep
  split_kernel<<<((Nn * 256) + 255) / 256, 256, 0, stream>>>(x, xsh, xsl, Nn * 256);
  tsplit_kernel<<<(256 * 512 + 255) / 256, 256, 0, stream>>>(W1, W1th, W1tl, 256, 512);
  tsplit_kernel<<<(512 * 512 + 255) / 256, 256, 0, stream>>>(W2, W2th, W2tl, 512, 512);
  tsplit_kernel<<<(512 * 64 + 255) / 256, 256, 0, stream>>>(W3, W3th, W3tl, 512, 64);

  int gm = (Nn + 127) / 128;
  int ga = (Nn + 3) / 4;
  // layer 1: 256 -> 8x64 concat
  gemm_split<true><<<dim3(gm, 8), 256, 0, stream>>>(xsh, xsl, W1th, W1tl, Hb16, nullptr, Nn, 256, 512);
  alpha8b_kernel<<<Nn, 512, 0, stream>>>(Hb16, asrc1, adst1, als, ald, Nn);
  agg8_kernel<<<ga, 256, 0, stream>>>(Hb16, als, ald, b1, row_ptr, src_sorted, Ahb, Alb, Nn);
  // layer 2: 512 -> 8x64 concat
  gemm_split<true><<<dim3(gm, 8), 256, 0, stream>>>(Ahb, Alb, W2th, W2tl, Hb16, nullptr, Nn, 512, 512);
  alpha8b_kernel<<<Nn, 512, 0, stream>>>(Hb16, asrc2, adst2, als, ald, Nn);
  agg8_kernel<<<ga, 256, 0, stream>>>(Hb16, als, ald, b2, row_ptr, src_sorted, Ahb, Alb, Nn);
  // layer 3: 512 -> 64, 1 head
  gemm_split<false><<<dim3(gm, 1), 256, 0, stream>>>(Ahb, Alb, W3th, W3tl, nullptr, Hb3, Nn, 512, 64);
  alpha1_kernel<<<Nn, 64, 0, stream>>>(Hb3, asrc3, adst3, als, ald, Nn);
  agg1_kernel<<<ga, 256, 0, stream>>>(Hb3, als, ald, b3, row_ptr, src_sorted, X3, Nn);
  // classifier
  cls_kernel<<<Nn, 64, 0, stream>>>(X3, linW, linb, out, Nn);
}

// Round 4
// 245.650 us; speedup vs baseline: 1.7815x; 1.3360x over previous
//
#include <hip/hip_runtime.h>
#include <cmath>

#define NEG 0.2f

typedef __bf16 bf16x8 __attribute__((ext_vector_type(8)));
typedef float  f32x4  __attribute__((ext_vector_type(4)));

__device__ __forceinline__ void async16(const __bf16* g, __bf16* l) {
  __builtin_amdgcn_global_load_lds(
      (const __attribute__((address_space(1))) void*)g,
      (__attribute__((address_space(3))) void*)l, 16, 0, 0);
}
__device__ __forceinline__ f32x4 mfma16(bf16x8 a, bf16x8 b, f32x4 c) {
  return __builtin_amdgcn_mfma_f32_16x16x32_bf16(a, b, c, 0, 0, 0);
}

// ---------------- CSR build ----------------
__global__ void count_kernel(const int* __restrict__ ei, int* __restrict__ counts, int E, int Nn) {
  int e = blockIdx.x * blockDim.x + threadIdx.x;
  if (e >= E + Nn) return;
  int d = (e < E) ? ei[E + e] : (e - E);
  atomicAdd(&counts[d], 1);
}

__global__ __launch_bounds__(1024) void scan_kernel(const int* __restrict__ counts,
                                                    int* __restrict__ row_ptr,
                                                    int* __restrict__ cursor,
                                                    int n, int total) {
  __shared__ int sums[1024];
  int t = threadIdx.x;
  int per = (n + 1023) >> 10;
  int base = t * per;
  int s = 0;
  for (int i = 0; i < per; ++i) { int idx = base + i; if (idx < n) s += counts[idx]; }
  sums[t] = s;
  __syncthreads();
  for (int st = 1; st < 1024; st <<= 1) {
    int v = (t >= st) ? sums[t - st] : 0;
    __syncthreads();
    sums[t] += v;
    __syncthreads();
  }
  int off = (t == 0) ? 0 : sums[t - 1];
  for (int i = 0; i < per; ++i) {
    int idx = base + i;
    if (idx < n) { row_ptr[idx] = off; cursor[idx] = off; off += counts[idx]; }
  }
  if (t == 0) row_ptr[n] = total;
}

__global__ void scatter_kernel(const int* __restrict__ ei, int* __restrict__ cursor,
                               int* __restrict__ src_sorted, int E, int Nn) {
  int e = blockIdx.x * blockDim.x + threadIdx.x;
  if (e >= E + Nn) return;
  int s, d;
  if (e < E) { s = ei[e]; d = ei[E + e]; } else { s = e - E; d = e - E; }
  int pos = atomicAdd(&cursor[d], 1);
  src_sorted[pos] = s;
}

// ---------------- fused prep: zero counts, split x, transpose+split W1/W2/W3 --
__global__ void prep_kernel(const float* __restrict__ x, __bf16* __restrict__ xsh,
                            __bf16* __restrict__ xsl,
                            const float* __restrict__ W1, __bf16* __restrict__ W1th,
                            __bf16* __restrict__ W1tl,
                            const float* __restrict__ W2, __bf16* __restrict__ W2th,
                            __bf16* __restrict__ W2tl,
                            const float* __restrict__ W3, __bf16* __restrict__ W3th,
                            __bf16* __restrict__ W3tl,
                            int* __restrict__ counts, int Nn) {
  int i = blockIdx.x * blockDim.x + threadIdx.x;
  if (i < Nn) { counts[i] = 0; return; }
  i -= Nn;
  int nx = Nn * 256;
  if (i < nx) {
    float v = x[i];
    __bf16 h = (__bf16)v;
    xsh[i] = h;
    xsl[i] = (__bf16)(v - (float)h);
    return;
  }
  i -= nx;
  if (i < 256 * 512) {
    int k = i / 512, c = i % 512;
    float v = W1[i];
    __bf16 h = (__bf16)v;
    W1th[(size_t)c * 256 + k] = h;
    W1tl[(size_t)c * 256 + k] = (__bf16)(v - (float)h);
    return;
  }
  i -= 256 * 512;
  if (i < 512 * 512) {
    int k = i / 512, c = i % 512;
    float v = W2[i];
    __bf16 h = (__bf16)v;
    W2th[(size_t)c * 512 + k] = h;
    W2tl[(size_t)c * 512 + k] = (__bf16)(v - (float)h);
    return;
  }
  i -= 512 * 512;
  if (i < 512 * 64) {
    int k = i / 64, c = i % 64;
    float v = W3[i];
    __bf16 h = (__bf16)v;
    W3th[(size_t)c * 512 + k] = h;
    W3tl[(size_t)c * 512 + k] = (__bf16)(v - (float)h);
    return;
  }
}

// ---------------- split-bf16 MFMA GEMM v2 + fused alpha ----------------
// C[M,Nc] = (Ah+Al)@(Bh+Bl), Bt pre-transposed [Nc][K]. BM=128, BN=64, BK=64.
// 4 waves; wave owns 32 rows x 64 cols (fm=2, fn=4). Single LDS buffer, 48KB.
// Staging: K-major lane map (8 lanes x 128B per row) + XOR swizzle slot^=(row&7)
// on BOTH source and read side (global_load_lds dest must stay linear).
// Epilogue: fused alpha_src/alpha_dst dot products (BN=64 == one head).
template <bool BF16OUT, bool SWZ>
__global__ __launch_bounds__(256, 3) void gemm_v2(
    const __bf16* __restrict__ Ah, const __bf16* __restrict__ Al,
    const __bf16* __restrict__ Bth, const __bf16* __restrict__ Btl,
    __bf16* __restrict__ Cb, float* __restrict__ Cf,
    const float* __restrict__ asrc, const float* __restrict__ adst,
    float* __restrict__ als, float* __restrict__ ald,
    int M, int K, int Nc, int PX, int hstride) {
  __shared__ __bf16 sAh[128 * 64], sAl[128 * 64], sBh[64 * 64], sBl[64 * 64];

  int x, y;
  if (SWZ) {
    int p = blockIdx.x;          // 64*PX blocks; XCD = p%8 (round-robin dispatch)
    int c = p & 7, j = p >> 3;   // panels c*PX..c*PX+PX-1 pinned to XCD c
    x = c * PX + (j >> 3);
    y = j & 7;
  } else {
    x = blockIdx.x;
    y = 0;
  }
  int rowBase = x * 128, colBase = y * 64;
  if (rowBase >= M) return;

  int tid = threadIdx.x;
  int lane = tid & 63, wave = tid >> 6;
  int r16 = lane & 15, koct = lane >> 4, msk = r16 & 7;

  f32x4 acc[2][4] = {};

  for (int k0 = 0; k0 < K; k0 += 64) {
    __syncthreads();  // prev tile's ds_reads done
    // ---- stage A (4 rounds per split) ----
#pragma unroll
    for (int r = 0; r < 4; ++r) {
      int flat = r * 256 + tid;
      int row = flat >> 3;
      int grow = rowBase + row;
      if (grow >= M) grow = M - 1;
      int s = (flat & 7) ^ (row & 7);
      size_t go = (size_t)grow * K + k0 + s * 8;
      int lb = (r * 256 + wave * 64) * 8;  // wave-uniform dest (HW adds lane*16B)
      async16(Ah + go, sAh + lb);
      async16(Al + go, sAl + lb);
    }
    // ---- stage B (2 rounds per split) ----
#pragma unroll
    for (int r = 0; r < 2; ++r) {
      int flat = r * 256 + tid;
      int col = flat >> 3;
      int s = (flat & 7) ^ (col & 7);
      size_t go = (size_t)(colBase + col) * K + k0 + s * 8;
      int lb = (r * 256 + wave * 64) * 8;
      async16(Bth + go, sBh + lb);
      async16(Btl + go, sBl + lb);
    }
    __syncthreads();  // vmcnt drained before barrier -> staged data visible

#pragma unroll
    for (int kk = 0; kk < 2; ++kk) {
      bf16x8 ah[2], al[2], bh[4], bl[4];
#pragma unroll
      for (int fm = 0; fm < 2; ++fm) {
        int off = (wave * 32 + fm * 16 + r16) * 64 + (((kk * 4 + koct) ^ msk) * 8);
        ah[fm] = *reinterpret_cast<const bf16x8*>(sAh + off);
        al[fm] = *reinterpret_cast<const bf16x8*>(sAl + off);
      }
#pragma unroll
      for (int fn = 0; fn < 4; ++fn) {
        int off = (fn * 16 + r16) * 64 + (((kk * 4 + koct) ^ msk) * 8);
        bh[fn] = *reinterpret_cast<const bf16x8*>(sBh + off);
        bl[fn] = *reinterpret_cast<const bf16x8*>(sBl + off);
      }
#pragma unroll
      for (int fm = 0; fm < 2; ++fm)
#pragma unroll
        for (int fn = 0; fn < 4; ++fn) {
          acc[fm][fn] = mfma16(ah[fm], bh[fn], acc[fm][fn]);
          acc[fm][fn] = mfma16(al[fm], bh[fn], acc[fm][fn]);
          acc[fm][fn] = mfma16(ah[fm], bl[fn], acc[fm][fn]);
        }
    }
  }

  // ---- epilogue: C write + fused alpha ----
  int head = y;
  float asv[4], adv[4];
#pragma unroll
  for (int fn = 0; fn < 4; ++fn) {
    asv[fn] = asrc[head * 64 + fn * 16 + r16];
    adv[fn] = adst[head * 64 + fn * 16 + r16];
  }
#pragma unroll
  for (int fm = 0; fm < 2; ++fm)
#pragma unroll
    for (int r = 0; r < 4; ++r) {
      int row = rowBase + wave * 32 + fm * 16 + koct * 4 + r;
      float ps = 0.f, pd = 0.f;
#pragma unroll
      for (int fn = 0; fn < 4; ++fn) {
        float v = acc[fm][fn][r];
        ps = fmaf(v, asv[fn], ps);
        pd = fmaf(v, adv[fn], pd);
        if (row < M) {
          int col = colBase + fn * 16 + r16;
          if (BF16OUT) Cb[(size_t)row * Nc + col] = (__bf16)v;
          else         Cf[(size_t)row * Nc + col] = v;
        }
      }
#pragma unroll
      for (int sft = 1; sft < 16; sft <<= 1) {
        ps += __shfl_xor(ps, sft);
        pd += __shfl_xor(pd, sft);
      }
      if (r16 == 0 && row < M) {
        als[(size_t)row * hstride + head] = ps;
        ald[(size_t)row * hstride + head] = pd;
      }
    }
}

// ---------------- fused softmax+aggregate, 8 heads: one WAVE per node --------
__global__ __launch_bounds__(256) void agg8_kernel(const __bf16* __restrict__ Hb,  // [N,512]
                                                   const float* __restrict__ als,  // [N,8]
                                                   const float* __restrict__ ald,  // [N,8]
                                                   const float* __restrict__ bias, // [512]
                                                   const int* __restrict__ row_ptr,
                                                   const int* __restrict__ src_sorted,
                                                   __bf16* __restrict__ Oh,        // [N,512]
                                                   __bf16* __restrict__ Ol,        // [N,512]
                                                   int Nn) {
  int n = (blockIdx.x * 256 + threadIdx.x) >> 6;
  if (n >= Nn) return;
  int lane = threadIdx.x & 63;
  int hh = lane >> 3;
  int start = row_ptr[n], deg = row_ptr[n + 1] - start;
  float aldn = ald[n * 8 + hh];

  // per-head neighbor max of als (leaky_relu monotone)
  float pm = -INFINITY;
  for (int e = (lane >> 3); e < deg; e += 8)
    pm = fmaxf(pm, als[src_sorted[start + e] * 8 + (lane & 7)]);
  pm = fmaxf(pm, __shfl_xor(pm, 8));
  pm = fmaxf(pm, __shfl_xor(pm, 16));
  pm = fmaxf(pm, __shfl_xor(pm, 32));
  float m = __shfl(pm, hh) + aldn;
  m = m > 0.f ? m : NEG * m;

  // 4-deep gather; every lane computes its head's weight redundantly
  float acc[8] = {};
  float ssum = 0.f;
  const __bf16* hcol = Hb + lane * 8;
  for (int e0 = 0; e0 < deg; e0 += 4) {
    int idx[4];
    float av[4];
    bf16x8 v[4];
#pragma unroll
    for (int i = 0; i < 4; ++i) {
      int e = e0 + i;
      if (e > deg - 1) e = deg - 1;
      idx[i] = src_sorted[start + e];
    }
#pragma unroll
    for (int i = 0; i < 4; ++i) av[i] = als[idx[i] * 8 + hh];
#pragma unroll
    for (int i = 0; i < 4; ++i)
      v[i] = *reinterpret_cast<const bf16x8*>(hcol + (size_t)idx[i] * 512);
#pragma unroll
    for (int i = 0; i < 4; ++i) {
      float l = av[i] + aldn;
      l = l > 0.f ? l : NEG * l;
      float w = (e0 + i < deg) ? expf(l - m) : 0.f;
      ssum += w;
#pragma unroll
      for (int j = 0; j < 8; ++j) acc[j] = fmaf(w, (float)v[i][j], acc[j]);
    }
  }

  float inv = 1.f / (ssum + 1e-16f);
  bf16x8 vh, vl;
#pragma unroll
  for (int j = 0; j < 8; ++j) {
    float v = acc[j] * inv + bias[lane * 8 + j];
    v = v > 0.f ? v : expm1f(v);
    __bf16 h = (__bf16)v;
    vh[j] = h;
    vl[j] = (__bf16)(v - (float)h);
  }
  *reinterpret_cast<bf16x8*>(Oh + (size_t)n * 512 + lane * 8) = vh;
  *reinterpret_cast<bf16x8*>(Ol + (size_t)n * 512 + lane * 8) = vl;
}

// ------- fused aggregate (1 head) + classifier + log_softmax: wave per node --
__global__ __launch_bounds__(256) void agg1cls_kernel(const float* __restrict__ Hf, // [N,64]
                                                      const float* __restrict__ als,
                                                      const float* __restrict__ ald,
                                                      const float* __restrict__ bias,
                                                      const int* __restrict__ row_ptr,
                                                      const int* __restrict__ src_sorted,
                                                      const float* __restrict__ lw,  // [64,2]
                                                      const float* __restrict__ lb,  // [2]
                                                      float* __restrict__ out,       // [N,2]
                                                      int Nn) {
  int n = (blockIdx.x * 256 + threadIdx.x) >> 6;
  if (n >= Nn) return;
  int lane = threadIdx.x & 63;
  int start = row_ptr[n], deg = row_ptr[n + 1] - start;
  float aldn = ald[n];

  float pm = -INFINITY;
  for (int e = lane; e < deg; e += 64) pm = fmaxf(pm, als[src_sorted[start + e]]);
  for (int s = 32; s; s >>= 1) pm = fmaxf(pm, __shfl_xor(pm, s));
  float m = pm + aldn;
  m = m > 0.f ? m : NEG * m;

  float acc = 0.f, ssum = 0.f;
  for (int e0 = 0; e0 < deg; e0 += 4) {
    int idx[4];
    float av[4], hv[4];
#pragma unroll
    for (int i = 0; i < 4; ++i) {
      int e = e0 + i;
      if (e > deg - 1) e = deg - 1;
      idx[i] = src_sorted[start + e];
    }
#pragma unroll
    for (int i = 0; i < 4; ++i) av[i] = als[idx[i]];
#pragma unroll
    for (int i = 0; i < 4; ++i) hv[i] = Hf[(size_t)idx[i] * 64 + lane];
#pragma unroll
    for (int i = 0; i < 4; ++i) {
      float l = av[i] + aldn;
      l = l > 0.f ? l : NEG * l;
      float w = (e0 + i < deg) ? expf(l - m) : 0.f;
      ssum += w;
      acc = fmaf(w, hv[i], acc);
    }
  }
  float o = acc / (ssum + 1e-16f) + bias[lane];

  // classifier + log_softmax
  float p0 = o * lw[lane * 2 + 0];
  float p1 = o * lw[lane * 2 + 1];
  for (int s = 32; s; s >>= 1) {
    p0 += __shfl_xor(p0, s);
    p1 += __shfl_xor(p1, s);
  }
  if (lane == 0) {
    p0 += lb[0];
    p1 += lb[1];
    float mx = fmaxf(p0, p1);
    float lse = mx + logf(expf(p0 - mx) + expf(p1 - mx));
    out[n * 2 + 0] = p0 - lse;
    out[n * 2 + 1] = p1 - lse;
  }
}

extern "C" void kernel_launch(void* const* d_in, const int* in_sizes, int n_in,
                              void* d_out, int out_size, void* d_ws, size_t ws_size,
                              hipStream_t stream) {
  (void)n_in; (void)out_size; (void)ws_size;
  const float* x     = (const float*)d_in[0];
  const int*   ei    = (const int*)d_in[1];
  const float* W1    = (const float*)d_in[2];
  const float* asrc1 = (const float*)d_in[3];
  const float* adst1 = (const float*)d_in[4];
  const float* b1    = (const float*)d_in[5];
  const float* W2    = (const float*)d_in[6];
  const float* asrc2 = (const float*)d_in[7];
  const float* adst2 = (const float*)d_in[8];
  const float* b2    = (const float*)d_in[9];
  const float* W3    = (const float*)d_in[10];
  const float* asrc3 = (const float*)d_in[11];
  const float* adst3 = (const float*)d_in[12];
  const float* b3    = (const float*)d_in[13];
  const float* linW  = (const float*)d_in[14];
  const float* linb  = (const float*)d_in[15];
  float* out = (float*)d_out;

  int Nn = in_sizes[0] / 256;
  int E  = in_sizes[1] / 2;
  int E2 = E + Nn;

  char* w = (char*)d_ws;
  auto carve = [&](size_t bytes) {
    char* p = w;
    w += (bytes + 63) & ~(size_t)63;
    return p;
  };
  __bf16* xsh  = (__bf16*)carve((size_t)Nn * 256 * 2);
  __bf16* xsl  = (__bf16*)carve((size_t)Nn * 256 * 2);
  __bf16* Ahb  = (__bf16*)carve((size_t)Nn * 512 * 2);
  __bf16* Alb  = (__bf16*)carve((size_t)Nn * 512 * 2);
  __bf16* Hb16 = (__bf16*)carve((size_t)Nn * 512 * 2);
  float*  Hb3  = (float*)carve((size_t)Nn * 64 * 4);
  float*  als  = (float*)carve((size_t)Nn * 8 * 4);
  float*  ald  = (float*)carve((size_t)Nn * 8 * 4);
  __bf16* W1th = (__bf16*)carve(256 * 512 * 2);
  __bf16* W1tl = (__bf16*)carve(256 * 512 * 2);
  __bf16* W2th = (__bf16*)carve(512 * 512 * 2);
  __bf16* W2tl = (__bf16*)carve(512 * 512 * 2);
  __bf16* W3th = (__bf16*)carve(512 * 64 * 2);
  __bf16* W3tl = (__bf16*)carve(512 * 64 * 2);
  int* counts     = (int*)carve((size_t)Nn * 4);
  int* cursor     = (int*)carve((size_t)Nn * 4);
  int* row_ptr    = (int*)carve(((size_t)Nn + 1) * 4);
  int* src_sorted = (int*)carve((size_t)E2 * 4);

  // prep (also zeros counts) + CSR build
  int prep_total = Nn + Nn * 256 + 256 * 512 + 512 * 512 + 512 * 64;
  prep_kernel<<<(prep_total + 255) / 256, 256, 0, stream>>>(
      x, xsh, xsl, W1, W1th, W1tl, W2, W2th, W2tl, W3, W3th, W3tl, counts, Nn);
  count_kernel<<<(E2 + 255) / 256, 256, 0, stream>>>(ei, counts, E, Nn);
  scan_kernel<<<1, 1024, 0, stream>>>(counts, row_ptr, cursor, Nn, E2);
  scatter_kernel<<<(E2 + 255) / 256, 256, 0, stream>>>(ei, cursor, src_sorted, E, Nn);

  int gx = (Nn + 127) / 128;          // 79
  int PX = (gx + 7) / 8;              // 10
  int nblk = 64 * PX;                 // 640 physical blocks (8 XCD * PX * 8 cols)
  int ga = (Nn + 3) / 4;

  // layer 1: 256 -> 8x64 concat (alpha fused)
  gemm_v2<true, true><<<nblk, 256, 0, stream>>>(xsh, xsl, W1th, W1tl, Hb16, nullptr,
                                                asrc1, adst1, als, ald, Nn, 256, 512, PX, 8);
  agg8_kernel<<<ga, 256, 0, stream>>>(Hb16, als, ald, b1, row_ptr, src_sorted, Ahb, Alb, Nn);
  // layer 2: 512 -> 8x64 concat
  gemm_v2<true, true><<<nblk, 256, 0, stream>>>(Ahb, Alb, W2th, W2tl, Hb16, nullptr,
                                                asrc2, adst2, als, ald, Nn, 512, 512, PX, 8);
  agg8_kernel<<<ga, 256, 0, stream>>>(Hb16, als, ald, b2, row_ptr, src_sorted, Ahb, Alb, Nn);
  // layer 3: 512 -> 64, 1 head (alpha fused, fp32 out)
  gemm_v2<false, false><<<gx, 256, 0, stream>>>(Ahb, Alb, W3th, W3tl, nullptr, Hb3,
                                                asrc3, adst3, als, ald, Nn, 512, 64, 0, 1);
  // aggregate + classifier + log_softmax
  agg1cls_kernel<<<ga, 256, 0, stream>>>(Hb3, als, ald, b3, row_ptr, src_sorted,
                                         linW, linb, out, Nn);
}

// Round 5
// 215.516 us; speedup vs baseline: 2.0306x; 1.1398x over previous
//
#include <hip/hip_runtime.h>
#include <cmath>

#define NEG 0.2f

typedef __bf16 bf16x8 __attribute__((ext_vector_type(8)));
typedef float  f32x4  __attribute__((ext_vector_type(4)));

__device__ __forceinline__ void async16(const __bf16* g, __bf16* l) {
  __builtin_amdgcn_global_load_lds(
      (const __attribute__((address_space(1))) void*)g,
      (__attribute__((address_space(3))) void*)l, 16, 0, 0);
}
__device__ __forceinline__ f32x4 mfma16(bf16x8 a, bf16x8 b, f32x4 c) {
  return __builtin_amdgcn_mfma_f32_16x16x32_bf16(a, b, c, 0, 0, 0);
}

// ---------------- CSR build ----------------
__global__ void count_kernel(const int* __restrict__ ei, int* __restrict__ counts, int E, int Nn) {
  int e = blockIdx.x * blockDim.x + threadIdx.x;
  if (e >= E + Nn) return;
  int d = (e < E) ? ei[E + e] : (e - E);
  atomicAdd(&counts[d], 1);
}

__global__ __launch_bounds__(1024) void scan_kernel(const int* __restrict__ counts,
                                                    int* __restrict__ row_ptr,
                                                    int* __restrict__ cursor,
                                                    int n, int total) {
  __shared__ int sums[1024];
  int t = threadIdx.x;
  int per = (n + 1023) >> 10;
  int base = t * per;
  int s = 0;
  for (int i = 0; i < per; ++i) { int idx = base + i; if (idx < n) s += counts[idx]; }
  sums[t] = s;
  __syncthreads();
  for (int st = 1; st < 1024; st <<= 1) {
    int v = (t >= st) ? sums[t - st] : 0;
    __syncthreads();
    sums[t] += v;
    __syncthreads();
  }
  int off = (t == 0) ? 0 : sums[t - 1];
  for (int i = 0; i < per; ++i) {
    int idx = base + i;
    if (idx < n) { row_ptr[idx] = off; cursor[idx] = off; off += counts[idx]; }
  }
  if (t == 0) row_ptr[n] = total;
}

__global__ void scatter_kernel(const int* __restrict__ ei, int* __restrict__ cursor,
                               int* __restrict__ src_sorted, int E, int Nn) {
  int e = blockIdx.x * blockDim.x + threadIdx.x;
  if (e >= E + Nn) return;
  int s, d;
  if (e < E) { s = ei[e]; d = ei[E + e]; } else { s = e - E; d = e - E; }
  int pos = atomicAdd(&cursor[d], 1);
  src_sorted[pos] = s;
}

// ------- fused prep: zero counts, split x, transpose W1/W2/W3 (high only) ----
__global__ void prep_kernel(const float* __restrict__ x, __bf16* __restrict__ xsh,
                            __bf16* __restrict__ xsl,
                            const float* __restrict__ W1, __bf16* __restrict__ W1th,
                            const float* __restrict__ W2, __bf16* __restrict__ W2th,
                            const float* __restrict__ W3, __bf16* __restrict__ W3th,
                            int* __restrict__ counts, int Nn) {
  int i = blockIdx.x * blockDim.x + threadIdx.x;
  if (i < Nn) { counts[i] = 0; return; }
  i -= Nn;
  int nx = Nn * 256;
  if (i < nx) {
    float v = x[i];
    __bf16 h = (__bf16)v;
    xsh[i] = h;
    xsl[i] = (__bf16)(v - (float)h);
    return;
  }
  i -= nx;
  if (i < 256 * 512) {
    int k = i / 512, c = i % 512;
    W1th[(size_t)c * 256 + k] = (__bf16)W1[i];
    return;
  }
  i -= 256 * 512;
  if (i < 512 * 512) {
    int k = i / 512, c = i % 512;
    W2th[(size_t)c * 512 + k] = (__bf16)W2[i];
    return;
  }
  i -= 512 * 512;
  if (i < 512 * 64) {
    int k = i / 64, c = i % 64;
    W3th[(size_t)c * 512 + k] = (__bf16)W3[i];
    return;
  }
}

// ---------------- split-bf16 MFMA GEMM (2-pass) + fused alpha ----------------
// C[M,Nc] = (Ah+Al)@Bh, Bt pre-transposed [Nc][K]. BM=128, BN=64, BK=64.
// 4 waves; wave owns 32 rows x 64 cols. Single LDS buffer 40KB, XOR swizzle
// slot^=(row&7) on source AND read side. Epilogue: fused alpha dot products.
template <bool BF16OUT, bool SWZ>
__global__ __launch_bounds__(256, 4) void gemm_v2(
    const __bf16* __restrict__ Ah, const __bf16* __restrict__ Al,
    const __bf16* __restrict__ Bth,
    __bf16* __restrict__ Cb, float* __restrict__ Cf,
    const float* __restrict__ asrc, const float* __restrict__ adst,
    float* __restrict__ als, float* __restrict__ ald,
    int M, int K, int Nc, int PX, int hstride) {
  __shared__ __bf16 sAh[128 * 64], sAl[128 * 64], sBh[64 * 64];

  int x, y;
  if (SWZ) {
    int p = blockIdx.x;          // XCD = p%8 (round-robin dispatch)
    int c = p & 7, j = p >> 3;   // row-panels c*PX.. pinned to XCD c
    x = c * PX + (j >> 3);
    y = j & 7;
  } else {
    x = blockIdx.x;
    y = 0;
  }
  int rowBase = x * 128, colBase = y * 64;
  if (rowBase >= M) return;

  int tid = threadIdx.x;
  int lane = tid & 63, wave = tid >> 6;
  int r16 = lane & 15, koct = lane >> 4, msk = r16 & 7;

  f32x4 acc[2][4] = {};

  for (int k0 = 0; k0 < K; k0 += 64) {
    __syncthreads();  // prev tile's ds_reads done
#pragma unroll
    for (int r = 0; r < 4; ++r) {
      int flat = r * 256 + tid;
      int row = flat >> 3;
      int grow = rowBase + row;
      if (grow >= M) grow = M - 1;
      int s = (flat & 7) ^ (row & 7);
      size_t go = (size_t)grow * K + k0 + s * 8;
      int lb = (r * 256 + wave * 64) * 8;  // wave-uniform dest (HW adds lane*16B)
      async16(Ah + go, sAh + lb);
      async16(Al + go, sAl + lb);
    }
#pragma unroll
    for (int r = 0; r < 2; ++r) {
      int flat = r * 256 + tid;
      int col = flat >> 3;
      int s = (flat & 7) ^ (col & 7);
      size_t go = (size_t)(colBase + col) * K + k0 + s * 8;
      int lb = (r * 256 + wave * 64) * 8;
      async16(Bth + go, sBh + lb);
    }
    __syncthreads();  // vmcnt drained before barrier -> staged data visible

#pragma unroll
    for (int kk = 0; kk < 2; ++kk) {
      bf16x8 ah[2], al[2], bh[4];
#pragma unroll
      for (int fm = 0; fm < 2; ++fm) {
        int off = (wave * 32 + fm * 16 + r16) * 64 + (((kk * 4 + koct) ^ msk) * 8);
        ah[fm] = *reinterpret_cast<const bf16x8*>(sAh + off);
        al[fm] = *reinterpret_cast<const bf16x8*>(sAl + off);
      }
#pragma unroll
      for (int fn = 0; fn < 4; ++fn) {
        int off = (fn * 16 + r16) * 64 + (((kk * 4 + koct) ^ msk) * 8);
        bh[fn] = *reinterpret_cast<const bf16x8*>(sBh + off);
      }
#pragma unroll
      for (int fm = 0; fm < 2; ++fm)
#pragma unroll
        for (int fn = 0; fn < 4; ++fn) {
          acc[fm][fn] = mfma16(ah[fm], bh[fn], acc[fm][fn]);
          acc[fm][fn] = mfma16(al[fm], bh[fn], acc[fm][fn]);
        }
    }
  }

  // ---- epilogue: C write + fused alpha ----
  int head = y;
  float asv[4], adv[4];
#pragma unroll
  for (int fn = 0; fn < 4; ++fn) {
    asv[fn] = asrc[head * 64 + fn * 16 + r16];
    adv[fn] = adst[head * 64 + fn * 16 + r16];
  }
#pragma unroll
  for (int fm = 0; fm < 2; ++fm)
#pragma unroll
    for (int r = 0; r < 4; ++r) {
      int row = rowBase + wave * 32 + fm * 16 + koct * 4 + r;
      float ps = 0.f, pd = 0.f;
#pragma unroll
      for (int fn = 0; fn < 4; ++fn) {
        float v = acc[fm][fn][r];
        ps = fmaf(v, asv[fn], ps);
        pd = fmaf(v, adv[fn], pd);
        if (row < M) {
          int col = colBase + fn * 16 + r16;
          if (BF16OUT) Cb[(size_t)row * Nc + col] = (__bf16)v;
          else         Cf[(size_t)row * Nc + col] = v;
        }
      }
#pragma unroll
      for (int sft = 1; sft < 16; sft <<= 1) {
        ps += __shfl_xor(ps, sft);
        pd += __shfl_xor(pd, sft);
      }
      if (r16 == 0 && row < M) {
        als[(size_t)row * hstride + head] = ps;
        ald[(size_t)row * hstride + head] = pd;
      }
    }
}

// ------- fused softmax+aggregate, 8 heads: one WAVE per node, ONE PASS -------
// Softmax is shift-invariant: use running shift mrun (init 0), rescale only if
// a logit exceeds mrun+24 (guards exp range; essentially never fires).
__global__ __launch_bounds__(256) void agg8_kernel(const __bf16* __restrict__ Hb,  // [N,512]
                                                   const float* __restrict__ als,  // [N,8]
                                                   const float* __restrict__ ald,  // [N,8]
                                                   const float* __restrict__ bias, // [512]
                                                   const int* __restrict__ row_ptr,
                                                   const int* __restrict__ src_sorted,
                                                   __bf16* __restrict__ Oh,        // [N,512]
                                                   __bf16* __restrict__ Ol,        // [N,512]
                                                   int Nn) {
  int n = (blockIdx.x * 256 + threadIdx.x) >> 6;
  if (n >= Nn) return;
  int lane = threadIdx.x & 63;
  int hh = lane >> 3;
  int start = row_ptr[n], deg = row_ptr[n + 1] - start;
  float aldn = ald[n * 8 + hh];

  float acc[8] = {};
  float ssum = 0.f;
  float mrun = 0.f;
  const __bf16* hcol = Hb + lane * 8;
  for (int e0 = 0; e0 < deg; e0 += 8) {
    int idx[8];
    float lv[8];
    bf16x8 v[8];
#pragma unroll
    for (int i = 0; i < 8; ++i) {
      int e = e0 + i;
      if (e > deg - 1) e = deg - 1;
      idx[i] = src_sorted[start + e];
    }
#pragma unroll
    for (int i = 0; i < 8; ++i) lv[i] = als[idx[i] * 8 + hh];
#pragma unroll
    for (int i = 0; i < 8; ++i)
      v[i] = *reinterpret_cast<const bf16x8*>(hcol + (size_t)idx[i] * 512);
    float lm = -INFINITY;
#pragma unroll
    for (int i = 0; i < 8; ++i) {
      float l = lv[i] + aldn;
      l = l > 0.f ? l : NEG * l;
      lv[i] = l;
      lm = fmaxf(lm, l);
    }
    if (__builtin_expect(lm > mrun + 24.f, 0)) {
      float sc = __expf(mrun - lm);
      ssum *= sc;
#pragma unroll
      for (int j = 0; j < 8; ++j) acc[j] *= sc;
      mrun = lm;
    }
#pragma unroll
    for (int i = 0; i < 8; ++i) {
      float w = (e0 + i < deg) ? __expf(lv[i] - mrun) : 0.f;
      ssum += w;
#pragma unroll
      for (int j = 0; j < 8; ++j) acc[j] = fmaf(w, (float)v[i][j], acc[j]);
    }
  }

  float inv = 1.f / (ssum + 1e-16f);
  bf16x8 vh, vl;
#pragma unroll
  for (int j = 0; j < 8; ++j) {
    float v = acc[j] * inv + bias[lane * 8 + j];
    v = v > 0.f ? v : expm1f(v);
    __bf16 h = (__bf16)v;
    vh[j] = h;
    vl[j] = (__bf16)(v - (float)h);
  }
  *reinterpret_cast<bf16x8*>(Oh + (size_t)n * 512 + lane * 8) = vh;
  *reinterpret_cast<bf16x8*>(Ol + (size_t)n * 512 + lane * 8) = vl;
}

// ------- fused aggregate (1 head, one-pass) + classifier + log_softmax ------
__global__ __launch_bounds__(256) void agg1cls_kernel(const float* __restrict__ Hf, // [N,64]
                                                      const float* __restrict__ als,
                                                      const float* __restrict__ ald,
                                                      const float* __restrict__ bias,
                                                      const int* __restrict__ row_ptr,
                                                      const int* __restrict__ src_sorted,
                                                      const float* __restrict__ lw,  // [64,2]
                                                      const float* __restrict__ lb,  // [2]
                                                      float* __restrict__ out,       // [N,2]
                                                      int Nn) {
  int n = (blockIdx.x * 256 + threadIdx.x) >> 6;
  if (n >= Nn) return;
  int lane = threadIdx.x & 63;
  int start = row_ptr[n], deg = row_ptr[n + 1] - start;
  float aldn = ald[n];

  float acc = 0.f, ssum = 0.f, mrun = 0.f;
  for (int e0 = 0; e0 < deg; e0 += 8) {
    int idx[8];
    float lv[8], hv[8];
#pragma unroll
    for (int i = 0; i < 8; ++i) {
      int e = e0 + i;
      if (e > deg - 1) e = deg - 1;
      idx[i] = src_sorted[start + e];
    }
#pragma unroll
    for (int i = 0; i < 8; ++i) lv[i] = als[idx[i]];
#pragma unroll
    for (int i = 0; i < 8; ++i) hv[i] = Hf[(size_t)idx[i] * 64 + lane];
    float lm = -INFINITY;
#pragma unroll
    for (int i = 0; i < 8; ++i) {
      float l = lv[i] + aldn;
      l = l > 0.f ? l : NEG * l;
      lv[i] = l;
      lm = fmaxf(lm, l);
    }
    if (__builtin_expect(lm > mrun + 24.f, 0)) {
      float sc = __expf(mrun - lm);
      ssum *= sc;
      acc *= sc;
      mrun = lm;
    }
#pragma unroll
    for (int i = 0; i < 8; ++i) {
      float w = (e0 + i < deg) ? __expf(lv[i] - mrun) : 0.f;
      ssum += w;
      acc = fmaf(w, hv[i], acc);
    }
  }
  float o = acc / (ssum + 1e-16f) + bias[lane];

  // classifier + log_softmax
  float p0 = o * lw[lane * 2 + 0];
  float p1 = o * lw[lane * 2 + 1];
  for (int s = 32; s; s >>= 1) {
    p0 += __shfl_xor(p0, s);
    p1 += __shfl_xor(p1, s);
  }
  if (lane == 0) {
    p0 += lb[0];
    p1 += lb[1];
    float mx = fmaxf(p0, p1);
    float lse = mx + logf(expf(p0 - mx) + expf(p1 - mx));
    out[n * 2 + 0] = p0 - lse;
    out[n * 2 + 1] = p1 - lse;
  }
}

extern "C" void kernel_launch(void* const* d_in, const int* in_sizes, int n_in,
                              void* d_out, int out_size, void* d_ws, size_t ws_size,
                              hipStream_t stream) {
  (void)n_in; (void)out_size; (void)ws_size;
  const float* x     = (const float*)d_in[0];
  const int*   ei    = (const int*)d_in[1];
  const float* W1    = (const float*)d_in[2];
  const float* asrc1 = (const float*)d_in[3];
  const float* adst1 = (const float*)d_in[4];
  const float* b1    = (const float*)d_in[5];
  const float* W2    = (const float*)d_in[6];
  const float* asrc2 = (const float*)d_in[7];
  const float* adst2 = (const float*)d_in[8];
  const float* b2    = (const float*)d_in[9];
  const float* W3    = (const float*)d_in[10];
  const float* asrc3 = (const float*)d_in[11];
  const float* adst3 = (const float*)d_in[12];
  const float* b3    = (const float*)d_in[13];
  const float* linW  = (const float*)d_in[14];
  const float* linb  = (const float*)d_in[15];
  float* out = (float*)d_out;

  int Nn = in_sizes[0] / 256;
  int E  = in_sizes[1] / 2;
  int E2 = E + Nn;

  char* w = (char*)d_ws;
  auto carve = [&](size_t bytes) {
    char* p = w;
    w += (bytes + 63) & ~(size_t)63;
    return p;
  };
  __bf16* xsh  = (__bf16*)carve((size_t)Nn * 256 * 2);
  __bf16* xsl  = (__bf16*)carve((size_t)Nn * 256 * 2);
  __bf16* Ahb  = (__bf16*)carve((size_t)Nn * 512 * 2);
  __bf16* Alb  = (__bf16*)carve((size_t)Nn * 512 * 2);
  __bf16* Hb16 = (__bf16*)carve((size_t)Nn * 512 * 2);
  float*  Hb3  = (float*)carve((size_t)Nn * 64 * 4);
  float*  als  = (float*)carve((size_t)Nn * 8 * 4);
  float*  ald  = (float*)carve((size_t)Nn * 8 * 4);
  __bf16* W1th = (__bf16*)carve(256 * 512 * 2);
  __bf16* W2th = (__bf16*)carve(512 * 512 * 2);
  __bf16* W3th = (__bf16*)carve(512 * 64 * 2);
  int* counts     = (int*)carve((size_t)Nn * 4);
  int* cursor     = (int*)carve((size_t)Nn * 4);
  int* row_ptr    = (int*)carve(((size_t)Nn + 1) * 4);
  int* src_sorted = (int*)carve((size_t)E2 * 4);

  // prep (also zeros counts) + CSR build
  int prep_total = Nn + Nn * 256 + 256 * 512 + 512 * 512 + 512 * 64;
  prep_kernel<<<(prep_total + 255) / 256, 256, 0, stream>>>(
      x, xsh, xsl, W1, W1th, W2, W2th, W3, W3th, counts, Nn);
  count_kernel<<<(E2 + 255) / 256, 256, 0, stream>>>(ei, counts, E, Nn);
  scan_kernel<<<1, 1024, 0, stream>>>(counts, row_ptr, cursor, Nn, E2);
  scatter_kernel<<<(E2 + 255) / 256, 256, 0, stream>>>(ei, cursor, src_sorted, E, Nn);

  int gx = (Nn + 127) / 128;          // 79
  int PX = (gx + 7) / 8;              // 10
  int nblk = 64 * PX;                 // 640 blocks (8 XCD * PX * 8 cols)
  int ga = (Nn + 3) / 4;

  // layer 1: 256 -> 8x64 concat (alpha fused)
  gemm_v2<true, true><<<nblk, 256, 0, stream>>>(xsh, xsl, W1th, Hb16, nullptr,
                                                asrc1, adst1, als, ald, Nn, 256, 512, PX, 8);
  agg8_kernel<<<ga, 256, 0, stream>>>(Hb16, als, ald, b1, row_ptr, src_sorted, Ahb, Alb, Nn);
  // layer 2: 512 -> 8x64 concat
  gemm_v2<true, true><<<nblk, 256, 0, stream>>>(Ahb, Alb, W2th, Hb16, nullptr,
                                                asrc2, adst2, als, ald, Nn, 512, 512, PX, 8);
  agg8_kernel<<<ga, 256, 0, stream>>>(Hb16, als, ald, b2, row_ptr, src_sorted, Ahb, Alb, Nn);
  // layer 3: 512 -> 64, 1 head (alpha fused, fp32 out)
  gemm_v2<false, false><<<gx, 256, 0, stream>>>(Ahb, Alb, W3th, nullptr, Hb3,
                                                asrc3, adst3, als, ald, Nn, 512, 64, 0, 1);
  // aggregate + classifier + log_softmax
  agg1cls_kernel<<<ga, 256, 0, stream>>>(Hb3, als, ald, b3, row_ptr, src_sorted,
                                         linW, linb, out, Nn);
}